// Round 1
// baseline (37697.751 us; speedup 1.0000x reference)
//
#include <hip/hip_runtime.h>
#include <hip/hip_bf16.h>
#include <cstdint>
#include <cstddef>

// ---------------------------------------------------------------------------
// StackedLayerNormGRU  (B=64, C_IN=256, H=512, T=1024)
//
// Strategy: precompute gate_x0 = raw(xs @ Wx0^T) + LN stats (parallel MFMA
// GEMM), then a 48-block persistent kernel runs the recurrence with a
// software pipeline needing only 2 global barriers per timestep:
//   P1(tau): z_h0[tau] = h0[tau-1]@Wh0^T ; z_x1[tau-1] = h0[tau-1]@Wx1^T ;
//            z_h1[tau-1] = h1[tau-2]@Wh1^T ; row-stat atomics
//   B1
//   P2(tau): combine -> h0[tau] (layer0), combine -> h1[tau-1] (layer1, out)
//   B2
// All GEMMs: bf16 MFMA 16x16x32, weights split hi+lo bf16 (2-term ~ fp32 W),
// h kept fp32 in registers, rounded to bf16 only as MFMA A-operand.
// ---------------------------------------------------------------------------

#define NBATCH 64
#define HDIM   512
#define THREE_H 1536
#define CINDIM 256
#define T_STEPS 1024
#define EPSLN 1e-5f
#define NBLK 48   // persistent kernel grid: 16 L0 blocks + 32 X1 blocks

typedef __bf16 bf8v __attribute__((ext_vector_type(8)));
typedef float f4 __attribute__((ext_vector_type(4)));

// ---- workspace layout (bytes) ----
static constexpr size_t OFF_BAR    = 0;                        // 2x u32 barrier
static constexpr size_t OFF_STATSA = 256;                      // [2][3][64][2] f32 = 3072
static constexpr size_t OFF_H0BF   = 3328;                     // 64*512 bf16 = 65536
static constexpr size_t OFF_H1BF   = 68864;                    // 65536
static constexpr size_t OFF_STATSX = 134400;                   // [1024][64][2] f32 = 524288
static constexpr size_t OFF_WH0HI  = 658688;                   // 1536*512 bf16 = 1572864 each
static constexpr size_t OFF_WH0LO  = OFF_WH0HI + 1572864;
static constexpr size_t OFF_WX1HI  = OFF_WH0LO + 1572864;
static constexpr size_t OFF_WX1LO  = OFF_WX1HI + 1572864;
static constexpr size_t OFF_WH1HI  = OFF_WX1LO + 1572864;
static constexpr size_t OFF_WH1LO  = OFF_WH1HI + 1572864;
static constexpr size_t OFF_WX0HI  = OFF_WH1LO + 1572864;      // 1536*256 bf16 = 786432
static constexpr size_t OFF_WX0LO  = OFF_WX0HI + 786432;
static constexpr size_t OFF_XST    = OFF_WX0LO + 786432;       // [1024][64][256] bf16 = 33554432
static constexpr size_t OFF_GX0    = OFF_XST + 33554432;       // [1024][64][1536] bf16 = 201326592
static constexpr size_t WS_NEEDED  = OFF_GX0 + 201326592;      // ~246.5 MB

__device__ __forceinline__ f4 mf(bf8v a, bf8v b, f4 c){
  return __builtin_amdgcn_mfma_f32_16x16x32_bf16(a, b, c, 0, 0, 0);
}
__device__ __forceinline__ float sigf(float x){ return 1.0f/(1.0f + __expf(-x)); }
__device__ __forceinline__ float tanhfast(float x){ return 1.0f - 2.0f/(__expf(2.0f*x) + 1.0f); }

// device-scope sense/epoch barrier (all NBLK blocks co-resident: 48 blocks)
__device__ __forceinline__ void gbar(unsigned int* bar, int nb){
  __threadfence();          // every thread drains + flushes its own stores
  __syncthreads();
  if (threadIdx.x == 0){
    unsigned int e = __hip_atomic_load(&bar[1], __ATOMIC_RELAXED, __HIP_MEMORY_SCOPE_AGENT);
    unsigned int o = __hip_atomic_fetch_add(&bar[0], 1u, __ATOMIC_ACQ_REL, __HIP_MEMORY_SCOPE_AGENT);
    if (o == (unsigned int)(nb - 1)){
      __hip_atomic_store(&bar[0], 0u, __ATOMIC_RELAXED, __HIP_MEMORY_SCOPE_AGENT);
      __hip_atomic_fetch_add(&bar[1], 1u, __ATOMIC_RELEASE, __HIP_MEMORY_SCOPE_AGENT);
    } else {
      while (__hip_atomic_load(&bar[1], __ATOMIC_ACQUIRE, __HIP_MEMORY_SCOPE_AGENT) == e){
        __builtin_amdgcn_s_sleep(1);
      }
    }
    __threadfence();        // acquire side: invalidate CU L1 for whole block
  }
  __syncthreads();
}

// ---- K0: zero head of workspace (barrier, statsA, h0/h1 bf16, statsX) ----
__global__ void k_zero(unsigned int* p, int nwords){
  for (int i = blockIdx.x*blockDim.x + threadIdx.x; i < nwords; i += gridDim.x*blockDim.x)
    p[i] = 0u;
}

// ---- K1: fp32 weight -> bf16 hi/lo split ----
__global__ void k_conv(const float* __restrict__ src, __hip_bfloat16* __restrict__ hi,
                       __hip_bfloat16* __restrict__ lo, int n){
  for (int i = blockIdx.x*blockDim.x + threadIdx.x; i < n; i += gridDim.x*blockDim.x){
    float w = src[i];
    __hip_bfloat16 h = __float2bfloat16(w);
    hi[i] = h;
    lo[i] = __float2bfloat16(w - __bfloat162float(h));
  }
}

// ---- K1b: xs [B][C][T] f32 -> xsT [T][B][C] bf16 ----
__global__ void k_tr(const float* __restrict__ xs, __hip_bfloat16* __restrict__ xsT){
  const int total = NBATCH * CINDIM * (T_STEPS/4);
  for (int idx = blockIdx.x*blockDim.x + threadIdx.x; idx < total; idx += gridDim.x*blockDim.x){
    int b  = idx >> 16;            // 256*256 per b
    int c  = (idx >> 8) & 255;
    int t4 = idx & 255;
    const float4 v = *(const float4*)(xs + ((size_t)b*CINDIM + c)*T_STEPS + t4*4);
    float vv[4] = {v.x, v.y, v.z, v.w};
    #pragma unroll
    for (int i = 0; i < 4; ++i)
      xsT[(size_t)(4*t4 + i)*(NBATCH*CINDIM) + b*CINDIM + c] = __float2bfloat16(vv[i]);
  }
}

// ---- K2: gate_x0 raw GEMM: z = xsT[t] @ Wx0^T (2-term hi/lo), + stat atomics ----
// grid: 16384 blocks = 1024 t * 16 strip-triples (32-wide), 256 threads
__global__ __launch_bounds__(256,1) void k_xgemm(unsigned char* __restrict__ ws){
  const int tid = threadIdx.x;
  const int bx = blockIdx.x;
  const int t = bx >> 4, s = bx & 15;
  const int lane = tid & 63, w = tid >> 6, l15 = lane & 15, lg = lane >> 4;

  const __hip_bfloat16* X  = (const __hip_bfloat16*)(ws + OFF_XST) + (size_t)t*(NBATCH*CINDIM);
  const __hip_bfloat16* WH = (const __hip_bfloat16*)(ws + OFF_WX0HI);
  const __hip_bfloat16* WL = (const __hip_bfloat16*)(ws + OFF_WX0LO);
  float* statsX = (float*)(ws + OFF_STATSX);
  __hip_bfloat16* GX0 = (__hip_bfloat16*)(ws + OFF_GX0) + (size_t)t*(NBATCH*THREE_H);

  __shared__ __hip_bfloat16 SB[2][2][96][72];

  f4 acc[6];
  #pragma unroll
  for (int i = 0; i < 6; ++i) acc[i] = f4{0.f,0.f,0.f,0.f};

  // A preload: 8 frags (K=256)
  bf8v A0[8];
  #pragma unroll
  for (int kk = 0; kk < 8; ++kk)
    A0[kk] = *(const bf8v*)(X + (16*w + l15)*CINDIM + kk*32 + 8*lg);

  // B chunks of K=64, double-buffered. 96 rows = 3 gate strips of 32.
  bf8v pre[6];
  #pragma unroll
  for (int rep = 0; rep < 6; ++rep){
    int idx = tid + rep*256; int half = idx >= 768 ? 1 : 0; int i2 = idx - half*768;
    int rr = i2 >> 3, ko = (i2 & 7)*8;
    int j = 32*s + (rr & 31) + 512*(rr >> 5);
    const __hip_bfloat16* sp = (half ? WL : WH) + (size_t)j*CINDIM;
    pre[rep] = *(const bf8v*)(sp + ko);
  }
  #pragma unroll
  for (int chk = 0; chk < 4; ++chk){
    #pragma unroll
    for (int rep = 0; rep < 6; ++rep){
      int idx = tid + rep*256; int half = idx >= 768 ? 1 : 0; int i2 = idx - half*768;
      int rr = i2 >> 3, ko = (i2 & 7)*8;
      *(bf8v*)&SB[chk & 1][half][rr][ko] = pre[rep];
    }
    __syncthreads();
    if (chk < 3){
      #pragma unroll
      for (int rep = 0; rep < 6; ++rep){
        int idx = tid + rep*256; int half = idx >= 768 ? 1 : 0; int i2 = idx - half*768;
        int rr = i2 >> 3, ko = (i2 & 7)*8;
        int j = 32*s + (rr & 31) + 512*(rr >> 5);
        const __hip_bfloat16* sp = (half ? WL : WH) + (size_t)j*CINDIM;
        pre[rep] = *(const bf8v*)(sp + (chk+1)*64 + ko);
      }
    }
    #pragma unroll
    for (int sub = 0; sub < 2; ++sub){
      int kk = 2*chk + sub; int ko = 32*sub + 8*lg;
      bf8v a = A0[kk];
      #pragma unroll
      for (int nf = 0; nf < 6; ++nf){
        bf8v bh = *(const bf8v*)&SB[chk & 1][0][16*nf + l15][ko];
        bf8v bl = *(const bf8v*)&SB[chk & 1][1][16*nf + l15][ko];
        acc[nf] = mf(a, bh, acc[nf]);
        acc[nf] = mf(a, bl, acc[nf]);
      }
    }
  }

  // store raw z (bf16) + per-row stat partials
  #pragma unroll
  for (int r = 0; r < 4; ++r){
    int row = 16*w + 4*lg + r;
    float sm = 0.f, sq = 0.f;
    #pragma unroll
    for (int nf = 0; nf < 6; ++nf){
      float v = acc[nf][r];
      sm += v; sq += v*v;
      int tc = 16*nf + l15;
      int j = 32*s + (tc & 31) + 512*(tc >> 5);
      GX0[(size_t)row*THREE_H + j] = __float2bfloat16(v);
    }
    #pragma unroll
    for (int m = 1; m < 16; m <<= 1){ sm += __shfl_xor(sm, m); sq += __shfl_xor(sq, m); }
    if (l15 == 0){
      atomicAdd(&statsX[((size_t)t*64 + row)*2 + 0], sm);
      atomicAdd(&statsX[((size_t)t*64 + row)*2 + 1], sq);
    }
  }
}

// ---- K2b: finalize x stats (sum,sumsq) -> (mean, rstd) in place ----
__global__ void k_statsx(float* __restrict__ sx){
  int i = blockIdx.x*blockDim.x + threadIdx.x;
  if (i < T_STEPS*NBATCH){
    float s = sx[2*i], q = sx[2*i+1];
    float m = s * (1.0f/1536.0f);
    float v = fmaxf(q * (1.0f/1536.0f) - m*m, 0.0f);
    sx[2*i] = m;
    sx[2*i+1] = rsqrtf(v + EPSLN);
  }
}

// ---- K3: persistent recurrent kernel, 48 blocks x 256 threads ----
__global__ __launch_bounds__(256,1) void k_rnn(
    const float* __restrict__ gx0g, const float* __restrict__ gx0b,
    const float* __restrict__ gh0g, const float* __restrict__ gh0b,
    const float* __restrict__ gx1g, const float* __restrict__ gx1b,
    const float* __restrict__ gh1g, const float* __restrict__ gh1b,
    unsigned char* __restrict__ ws, float* __restrict__ out)
{
  const int tid = threadIdx.x, bi = blockIdx.x;
  const int lane = tid & 63, w = tid >> 6, l15 = lane & 15, lg = lane >> 4;

  unsigned int* bar = (unsigned int*)(ws + OFF_BAR);
  float* statsA = (float*)(ws + OFF_STATSA);                 // [2][3][64][2] raw sums
  __hip_bfloat16* h0bf = (__hip_bfloat16*)(ws + OFF_H0BF);
  __hip_bfloat16* h1bf = (__hip_bfloat16*)(ws + OFF_H1BF);
  const float* statsX = (const float*)(ws + OFF_STATSX);     // [1024][64]{mean,rstd}
  const __hip_bfloat16* GX0 = (const __hip_bfloat16*)(ws + OFF_GX0);
  const __hip_bfloat16* W0H = (const __hip_bfloat16*)(ws + OFF_WH0HI);
  const __hip_bfloat16* W0L = (const __hip_bfloat16*)(ws + OFF_WH0LO);
  const __hip_bfloat16* X1H = (const __hip_bfloat16*)(ws + OFF_WX1HI);
  const __hip_bfloat16* X1L = (const __hip_bfloat16*)(ws + OFF_WX1LO);
  const __hip_bfloat16* H1H = (const __hip_bfloat16*)(ws + OFF_WH1HI);
  const __hip_bfloat16* H1L = (const __hip_bfloat16*)(ws + OFF_WH1LO);

  __shared__ __hip_bfloat16 SB[2][2][96][72];

  const bool isL0 = (bi < 16);
  const int s16 = bi - 16;

  // LN params for owned columns (loaded once)
  float PGXg[2][3], PGXb[2][3], PGHg[2][3], PGHb[2][3];  // L0
  float QXg[3], QXb[3], QHg[3], QHb[3];                  // X1
  if (isL0){
    #pragma unroll
    for (int fi = 0; fi < 2; ++fi)
      #pragma unroll
      for (int g = 0; g < 3; ++g){
        int j = 32*bi + l15 + 16*fi + 512*g;
        PGXg[fi][g] = gx0g[j]; PGXb[fi][g] = gx0b[j];
        PGHg[fi][g] = gh0g[j]; PGHb[fi][g] = gh0b[j];
      }
  } else {
    #pragma unroll
    for (int g = 0; g < 3; ++g){
      int j = 16*s16 + l15 + 512*g;
      QXg[g] = gx1g[j]; QXb[g] = gx1b[j];
      QHg[g] = gh1g[j]; QHb[g] = gh1b[j];
    }
  }

  float hp0[2][4] = {{0.f,0.f,0.f,0.f},{0.f,0.f,0.f,0.f}};
  float hp1[4] = {0.f,0.f,0.f,0.f};

  for (int tau = 0; tau <= T_STEPS; ++tau){
    const bool act = isL0 ? (tau < T_STEPS) : (tau >= 1);
    const int p = tau & 1;

    f4 acc[6]; f4 acc1[3];
    float gxraw[2][3][4], mx[4], rsx[4];

    // -------- P1: GEMMs + stats --------
    if (act){
      #pragma unroll
      for (int i = 0; i < 6; ++i) acc[i] = f4{0.f,0.f,0.f,0.f};
      #pragma unroll
      for (int i = 0; i < 3; ++i) acc1[i] = f4{0.f,0.f,0.f,0.f};

      if (isL0){
        // prefetch x-gate raw values + stats for this step (used in P2)
        #pragma unroll
        for (int r = 0; r < 4; ++r){
          int row = 16*w + 4*lg + r;
          mx[r]  = statsX[((size_t)tau*64 + row)*2 + 0];
          rsx[r] = statsX[((size_t)tau*64 + row)*2 + 1];
          #pragma unroll
          for (int fi = 0; fi < 2; ++fi)
            #pragma unroll
            for (int g = 0; g < 3; ++g)
              gxraw[fi][g][r] = __bfloat162float(
                GX0[(size_t)tau*(NBATCH*THREE_H) + (size_t)row*THREE_H
                    + (32*bi + l15 + 16*fi + 512*g)]);
        }
      }

      // A preload: h0 frags (both roles); h1 frags (X1 only)
      bf8v A0[16], A1[16];
      #pragma unroll
      for (int kk = 0; kk < 16; ++kk)
        A0[kk] = *(const bf8v*)(h0bf + (16*w + l15)*HDIM + kk*32 + 8*lg);
      if (!isL0){
        #pragma unroll
        for (int kk = 0; kk < 16; ++kk)
          A1[kk] = *(const bf8v*)(h1bf + (16*w + l15)*HDIM + kk*32 + 8*lg);
      }

      // B row -> source pointer (strip-triple layout)
      auto srcrow = [&](int rr, int half) -> const __hip_bfloat16* {
        if (isL0){
          int j = 32*bi + (rr & 31) + 512*(rr >> 5);
          return (half ? W0L : W0H) + (size_t)j*HDIM;
        }
        int r2 = (rr < 48) ? rr : (rr - 48);
        int j = 16*s16 + (r2 & 15) + 512*(r2 >> 4);
        if (rr < 48) return (half ? X1L : X1H) + (size_t)j*HDIM;
        return (half ? H1L : H1H) + (size_t)j*HDIM;
      };

      bf8v pre[6];
      #pragma unroll
      for (int rep = 0; rep < 6; ++rep){
        int idx = tid + rep*256; int half = idx >= 768 ? 1 : 0; int i2 = idx - half*768;
        int rr = i2 >> 3, ko = (i2 & 7)*8;
        pre[rep] = *(const bf8v*)(srcrow(rr, half) + ko);
      }
      #pragma unroll
      for (int chk = 0; chk < 8; ++chk){
        #pragma unroll
        for (int rep = 0; rep < 6; ++rep){
          int idx = tid + rep*256; int half = idx >= 768 ? 1 : 0; int i2 = idx - half*768;
          int rr = i2 >> 3, ko = (i2 & 7)*8;
          *(bf8v*)&SB[chk & 1][half][rr][ko] = pre[rep];
        }
        __syncthreads();
        if (chk < 7){
          #pragma unroll
          for (int rep = 0; rep < 6; ++rep){
            int idx = tid + rep*256; int half = idx >= 768 ? 1 : 0; int i2 = idx - half*768;
            int rr = i2 >> 3, ko = (i2 & 7)*8;
            pre[rep] = *(const bf8v*)(srcrow(rr, half) + (chk+1)*64 + ko);
          }
        }
        #pragma unroll
        for (int sub = 0; sub < 2; ++sub){
          int kk = 2*chk + sub; int ko = 32*sub + 8*lg;
          if (isL0){
            bf8v a = A0[kk];
            #pragma unroll
            for (int nf = 0; nf < 6; ++nf){
              bf8v bh = *(const bf8v*)&SB[chk & 1][0][16*nf + l15][ko];
              bf8v bl = *(const bf8v*)&SB[chk & 1][1][16*nf + l15][ko];
              acc[nf] = mf(a, bh, acc[nf]);
              acc[nf] = mf(a, bl, acc[nf]);
            }
          } else {
            bf8v a0 = A0[kk], a1 = A1[kk];
            #pragma unroll
            for (int nf = 0; nf < 3; ++nf){
              bf8v bh = *(const bf8v*)&SB[chk & 1][0][16*nf + l15][ko];
              bf8v bl = *(const bf8v*)&SB[chk & 1][1][16*nf + l15][ko];
              acc[nf] = mf(a0, bh, acc[nf]);
              acc[nf] = mf(a0, bl, acc[nf]);
              bf8v ch2 = *(const bf8v*)&SB[chk & 1][0][48 + 16*nf + l15][ko];
              bf8v cl2 = *(const bf8v*)&SB[chk & 1][1][48 + 16*nf + l15][ko];
              acc1[nf] = mf(a1, ch2, acc1[nf]);
              acc1[nf] = mf(a1, cl2, acc1[nf]);
            }
          }
        }
      }

      // row-stat atomics (raw sums), parity p
      if (isL0){
        float* st0 = statsA + ((size_t)p*3 + 0)*64*2;
        #pragma unroll
        for (int r = 0; r < 4; ++r){
          float sm = 0.f, sq = 0.f;
          #pragma unroll
          for (int nf = 0; nf < 6; ++nf){ float v = acc[nf][r]; sm += v; sq += v*v; }
          #pragma unroll
          for (int m = 1; m < 16; m <<= 1){ sm += __shfl_xor(sm, m); sq += __shfl_xor(sq, m); }
          if (l15 == 0){
            int row = 16*w + 4*lg + r;
            atomicAdd(&st0[row*2 + 0], sm);
            atomicAdd(&st0[row*2 + 1], sq);
          }
        }
      } else {
        float* st1 = statsA + ((size_t)p*3 + 1)*64*2;
        float* st2 = statsA + ((size_t)p*3 + 2)*64*2;
        #pragma unroll
        for (int r = 0; r < 4; ++r){
          float s1 = 0.f, q1 = 0.f, s2 = 0.f, q2 = 0.f;
          #pragma unroll
          for (int nf = 0; nf < 3; ++nf){
            float v = acc[nf][r];  s1 += v; q1 += v*v;
            float u = acc1[nf][r]; s2 += u; q2 += u*u;
          }
          #pragma unroll
          for (int m = 1; m < 16; m <<= 1){
            s1 += __shfl_xor(s1, m); q1 += __shfl_xor(q1, m);
            s2 += __shfl_xor(s2, m); q2 += __shfl_xor(q2, m);
          }
          if (l15 == 0){
            int row = 16*w + 4*lg + r;
            atomicAdd(&st1[row*2 + 0], s1); atomicAdd(&st1[row*2 + 1], q1);
            atomicAdd(&st2[row*2 + 0], s2); atomicAdd(&st2[row*2 + 1], q2);
          }
        }
      }
    }

    gbar(bar, NBLK);   // B1: stats complete, z visible

    // -------- P2: combine --------
    if (act){
      if (isL0){
        const float* st0 = statsA + ((size_t)p*3 + 0)*64*2;
        #pragma unroll
        for (int r = 0; r < 4; ++r){
          int row = 16*w + 4*lg + r;
          float sm = st0[row*2 + 0], sq = st0[row*2 + 1];
          float m  = sm * (1.0f/1536.0f);
          float vv = fmaxf(sq * (1.0f/1536.0f) - m*m, 0.0f);
          float rs = rsqrtf(vv + EPSLN);
          #pragma unroll
          for (int fi = 0; fi < 2; ++fi){
            float zr = acc[fi][r], zi = acc[2+fi][r], zn = acc[4+fi][r];
            float ghr = (zr - m)*rs*PGHg[fi][0] + PGHb[fi][0];
            float ghi = (zi - m)*rs*PGHg[fi][1] + PGHb[fi][1];
            float ghn = (zn - m)*rs*PGHg[fi][2] + PGHb[fi][2];
            float gxr = (gxraw[fi][0][r] - mx[r])*rsx[r]*PGXg[fi][0] + PGXb[fi][0];
            float gxi = (gxraw[fi][1][r] - mx[r])*rsx[r]*PGXg[fi][1] + PGXb[fi][1];
            float gxn = (gxraw[fi][2][r] - mx[r])*rsx[r]*PGXg[fi][2] + PGXb[fi][2];
            float rg = sigf(gxr + ghr);
            float ig = sigf(gxi + ghi);
            float nn = tanhfast(gxn + rg*ghn);
            float hn = nn + ig*(hp0[fi][r] - nn);
            hp0[fi][r] = hn;
            h0bf[row*HDIM + 32*bi + l15 + 16*fi] = __float2bfloat16(hn);
          }
        }
      } else {
        const int t1 = tau - 1;
        const float* st1 = statsA + ((size_t)p*3 + 1)*64*2;
        const float* st2 = statsA + ((size_t)p*3 + 2)*64*2;
        #pragma unroll
        for (int r = 0; r < 4; ++r){
          int row = 16*w + 4*lg + r;
          float m1 = st1[row*2+0]*(1.0f/1536.0f);
          float v1 = fmaxf(st1[row*2+1]*(1.0f/1536.0f) - m1*m1, 0.0f);
          float rs1 = rsqrtf(v1 + EPSLN);
          float m2 = st2[row*2+0]*(1.0f/1536.0f);
          float v2 = fmaxf(st2[row*2+1]*(1.0f/1536.0f) - m2*m2, 0.0f);
          float rs2 = rsqrtf(v2 + EPSLN);
          float gxr = (acc[0][r] - m1)*rs1*QXg[0] + QXb[0];
          float gxi = (acc[1][r] - m1)*rs1*QXg[1] + QXb[1];
          float gxn = (acc[2][r] - m1)*rs1*QXg[2] + QXb[2];
          float ghr = (acc1[0][r] - m2)*rs2*QHg[0] + QHb[0];
          float ghi = (acc1[1][r] - m2)*rs2*QHg[1] + QHb[1];
          float ghn = (acc1[2][r] - m2)*rs2*QHg[2] + QHb[2];
          float rg = sigf(gxr + ghr);
          float ig = sigf(gxi + ghi);
          float nn = tanhfast(gxn + rg*ghn);
          float hn = nn + ig*(hp1[r] - nn);
          hp1[r] = hn;
          int j = 16*s16 + l15;
          h1bf[row*HDIM + j] = __float2bfloat16(hn);
          out[(size_t)row*(HDIM*T_STEPS) + (size_t)j*T_STEPS + t1] = hn;
        }
      }
    }
    // block 0 zeroes the other-parity stat accumulators for step tau+1
    if (bi == 0){
      float* dst = statsA + (size_t)(p ^ 1)*3*64*2;
      for (int i = tid; i < 384; i += 256) dst[i] = 0.f;
    }

    gbar(bar, NBLK);   // B2: h published
  }
}

// ---------------------------------------------------------------------------
extern "C" void kernel_launch(void* const* d_in, const int* in_sizes, int n_in,
                              void* d_out, int out_size, void* d_ws, size_t ws_size,
                              hipStream_t stream) {
  const float* xs  = (const float*)d_in[0];
  const float* Wx0 = (const float*)d_in[1];
  const float* Wh0 = (const float*)d_in[2];
  const float* gx0g = (const float*)d_in[3];
  const float* gx0b = (const float*)d_in[4];
  const float* gh0g = (const float*)d_in[5];
  const float* gh0b = (const float*)d_in[6];
  const float* Wx1 = (const float*)d_in[7];
  const float* Wh1 = (const float*)d_in[8];
  const float* gx1g = (const float*)d_in[9];
  const float* gx1b = (const float*)d_in[10];
  const float* gh1g = (const float*)d_in[11];
  const float* gh1b = (const float*)d_in[12];

  unsigned char* ws = (unsigned char*)d_ws;
  float* out = (float*)d_out;
  (void)in_sizes; (void)n_in; (void)out_size; (void)ws_size;

  // K0: zero barrier + statsA + h0bf + h1bf + statsX  (head region)
  k_zero<<<256, 256, 0, stream>>>((unsigned int*)ws, (int)(OFF_WH0HI/4));

  // K1: weight hi/lo conversion
  k_conv<<<512, 256, 0, stream>>>(Wh0, (__hip_bfloat16*)(ws+OFF_WH0HI), (__hip_bfloat16*)(ws+OFF_WH0LO), THREE_H*HDIM);
  k_conv<<<512, 256, 0, stream>>>(Wx1, (__hip_bfloat16*)(ws+OFF_WX1HI), (__hip_bfloat16*)(ws+OFF_WX1LO), THREE_H*HDIM);
  k_conv<<<512, 256, 0, stream>>>(Wh1, (__hip_bfloat16*)(ws+OFF_WH1HI), (__hip_bfloat16*)(ws+OFF_WH1LO), THREE_H*HDIM);
  k_conv<<<512, 256, 0, stream>>>(Wx0, (__hip_bfloat16*)(ws+OFF_WX0HI), (__hip_bfloat16*)(ws+OFF_WX0LO), THREE_H*CINDIM);

  // K1b: xs transpose -> xsT bf16
  k_tr<<<4096, 256, 0, stream>>>(xs, (__hip_bfloat16*)(ws+OFF_XST));

  // K2: x-path GEMM for all timesteps (raw z + stat sums)
  k_xgemm<<<16384, 256, 0, stream>>>(ws);

  // K2b: finalize x stats
  k_statsx<<<256, 256, 0, stream>>>((float*)(ws+OFF_STATSX));

  // K3: persistent recurrence
  k_rnn<<<NBLK, 256, 0, stream>>>(gx0g, gx0b, gh0g, gh0b, gx1g, gx1b, gh1g, gh1b, ws, out);
}

// Round 2
// 22920.760 us; speedup vs baseline: 1.6447x; 1.6447x over previous
//
#include <hip/hip_runtime.h>
#include <hip/hip_bf16.h>
#include <cstdint>
#include <cstddef>

// ---------------------------------------------------------------------------
// StackedLayerNormGRU  (B=64, C_IN=256, H=512, T=1024)
//
// Round 2: replace fence-heavy central atomic barrier with a distributed
// flag barrier + per-access device-coherent (sc0 sc1) loads/stores for all
// cross-XCD data (h0/h1, LN stats, flags). No buffer_wbl2/buffer_inv in the
// steady state -> weights stay L2-resident; barrier cost ~ MALL round trips.
// ---------------------------------------------------------------------------

#define NBATCH 64
#define HDIM   512
#define THREE_H 1536
#define CINDIM 256
#define T_STEPS 1024
#define EPSLN 1e-5f
#define NBLK 48   // persistent kernel grid: 16 L0 blocks + 32 X1 blocks

typedef __bf16 bf8v __attribute__((ext_vector_type(8)));
typedef float f4 __attribute__((ext_vector_type(4)));
typedef float f2 __attribute__((ext_vector_type(2)));
typedef unsigned int u32x4 __attribute__((ext_vector_type(4)));

// ---- workspace layout (bytes) ----
static constexpr size_t OFF_BAR    = 0;                        // 48 flags x 128B
static constexpr size_t OFF_STATSA = 8192;                     // [2][3][64][2] f32 = 3072
static constexpr size_t OFF_H0BF   = 11264;                    // 64*512 bf16 = 65536
static constexpr size_t OFF_H1BF   = 76800;                    // 65536
static constexpr size_t OFF_STATSX = 142336;                   // [1024][64][2] f32 = 524288
static constexpr size_t OFF_WH0HI  = 666624;                   // 1536*512 bf16 = 1572864 each
static constexpr size_t OFF_WH0LO  = OFF_WH0HI + 1572864;
static constexpr size_t OFF_WX1HI  = OFF_WH0LO + 1572864;
static constexpr size_t OFF_WX1LO  = OFF_WX1HI + 1572864;
static constexpr size_t OFF_WH1HI  = OFF_WX1LO + 1572864;
static constexpr size_t OFF_WH1LO  = OFF_WH1HI + 1572864;
static constexpr size_t OFF_WX0HI  = OFF_WH1LO + 1572864;      // 1536*256 bf16 = 786432
static constexpr size_t OFF_WX0LO  = OFF_WX0HI + 786432;
static constexpr size_t OFF_XST    = OFF_WX0LO + 786432;       // [1024][64][256] bf16 = 33554432
static constexpr size_t OFF_GX0    = OFF_XST + 33554432;       // [1024][64][1536] bf16 = 201326592

__device__ __forceinline__ f4 mf(bf8v a, bf8v b, f4 c){
  return __builtin_amdgcn_mfma_f32_16x16x32_bf16(a, b, c, 0, 0, 0);
}
__device__ __forceinline__ float sigf(float x){ return 1.0f/(1.0f + __expf(-x)); }
__device__ __forceinline__ float tanhfast(float x){ return 1.0f - 2.0f/(__expf(2.0f*x) + 1.0f); }

// ---- device-coherent (MALL) access helpers: bypass per-XCD L2 ----
__device__ __forceinline__ bf8v ld16_cross(const void* p){
  u32x4 t;
  asm volatile("global_load_dwordx4 %0, %1, off sc0 sc1" : "=v"(t) : "v"(p));
  return __builtin_bit_cast(bf8v, t);
}
__device__ __forceinline__ f2 ld8_cross(const float* p){
  f2 v;
  asm volatile("global_load_dwordx2 %0, %1, off sc0 sc1" : "=v"(v) : "v"(p));
  return v;
}
__device__ __forceinline__ void st2_cross(__hip_bfloat16* p, unsigned int u){
  asm volatile("global_store_short %0, %1, off sc0 sc1" :: "v"(p), "v"(u));
}
__device__ __forceinline__ void st4_cross(float* p, float v){
  asm volatile("global_store_dword %0, %1, off sc0 sc1" :: "v"(p), "v"(v));
}
__device__ __forceinline__ void vm_drain(){
  asm volatile("s_waitcnt vmcnt(0)" ::: "memory");
  __builtin_amdgcn_sched_barrier(0);
}

// ---- distributed flag barrier: 48 flags, 128B apart, epoch-numbered ----
__device__ __forceinline__ void gbar(unsigned int* flags, unsigned int target){
  // release: all prior vmem (incl. sc1 stores + atomics) globally visible
  asm volatile("s_waitcnt vmcnt(0) lgkmcnt(0)" ::: "memory");
  __syncthreads();
  if (threadIdx.x == 0){
    unsigned int* myf = flags + (size_t)blockIdx.x * 32;
    asm volatile("global_store_dword %0, %1, off sc0 sc1" :: "v"(myf), "v"(target) : "memory");
  }
  const int lane = threadIdx.x & 63;
  const unsigned int* pf = flags + (size_t)lane * 32;
  for (;;){
    unsigned int v = target;
    if (lane < NBLK){
      asm volatile("global_load_dword %0, %1, off sc0 sc1\n\ts_waitcnt vmcnt(0)"
                   : "=v"(v) : "v"(pf) : "memory");
    }
    if (__all((int)(v >= target))) break;
    __builtin_amdgcn_s_sleep(1);
  }
  // no exit __syncthreads needed: entry sync already separates LDS epochs
}

// ---- K0: zero head of workspace (flags, statsA, h0/h1 bf16, statsX) ----
__global__ void k_zero(unsigned int* p, int nwords){
  for (int i = blockIdx.x*blockDim.x + threadIdx.x; i < nwords; i += gridDim.x*blockDim.x)
    p[i] = 0u;
}

// ---- K1: fp32 weight -> bf16 hi/lo split ----
__global__ void k_conv(const float* __restrict__ src, __hip_bfloat16* __restrict__ hi,
                       __hip_bfloat16* __restrict__ lo, int n){
  for (int i = blockIdx.x*blockDim.x + threadIdx.x; i < n; i += gridDim.x*blockDim.x){
    float w = src[i];
    __hip_bfloat16 h = __float2bfloat16(w);
    hi[i] = h;
    lo[i] = __float2bfloat16(w - __bfloat162float(h));
  }
}

// ---- K1b: xs [B][C][T] f32 -> xsT [T][B][C] bf16 ----
__global__ void k_tr(const float* __restrict__ xs, __hip_bfloat16* __restrict__ xsT){
  const int total = NBATCH * CINDIM * (T_STEPS/4);
  for (int idx = blockIdx.x*blockDim.x + threadIdx.x; idx < total; idx += gridDim.x*blockDim.x){
    int b  = idx >> 16;
    int c  = (idx >> 8) & 255;
    int t4 = idx & 255;
    const float4 v = *(const float4*)(xs + ((size_t)b*CINDIM + c)*T_STEPS + t4*4);
    float vv[4] = {v.x, v.y, v.z, v.w};
    #pragma unroll
    for (int i = 0; i < 4; ++i)
      xsT[(size_t)(4*t4 + i)*(NBATCH*CINDIM) + b*CINDIM + c] = __float2bfloat16(vv[i]);
  }
}

// ---- K2: gate_x0 raw GEMM: z = xsT[t] @ Wx0^T (2-term hi/lo), + stat atomics ----
__global__ __launch_bounds__(256,1) void k_xgemm(unsigned char* __restrict__ ws){
  const int tid = threadIdx.x;
  const int bx = blockIdx.x;
  const int t = bx >> 4, s = bx & 15;
  const int lane = tid & 63, w = tid >> 6, l15 = lane & 15, lg = lane >> 4;

  const __hip_bfloat16* X  = (const __hip_bfloat16*)(ws + OFF_XST) + (size_t)t*(NBATCH*CINDIM);
  const __hip_bfloat16* WH = (const __hip_bfloat16*)(ws + OFF_WX0HI);
  const __hip_bfloat16* WL = (const __hip_bfloat16*)(ws + OFF_WX0LO);
  float* statsX = (float*)(ws + OFF_STATSX);
  __hip_bfloat16* GX0 = (__hip_bfloat16*)(ws + OFF_GX0) + (size_t)t*(NBATCH*THREE_H);

  __shared__ __hip_bfloat16 SB[2][2][96][72];

  f4 acc[6];
  #pragma unroll
  for (int i = 0; i < 6; ++i) acc[i] = f4{0.f,0.f,0.f,0.f};

  bf8v A0[8];
  #pragma unroll
  for (int kk = 0; kk < 8; ++kk)
    A0[kk] = *(const bf8v*)(X + (16*w + l15)*CINDIM + kk*32 + 8*lg);

  bf8v pre[6];
  #pragma unroll
  for (int rep = 0; rep < 6; ++rep){
    int idx = tid + rep*256; int half = idx >= 768 ? 1 : 0; int i2 = idx - half*768;
    int rr = i2 >> 3, ko = (i2 & 7)*8;
    int j = 32*s + (rr & 31) + 512*(rr >> 5);
    const __hip_bfloat16* sp = (half ? WL : WH) + (size_t)j*CINDIM;
    pre[rep] = *(const bf8v*)(sp + ko);
  }
  #pragma unroll
  for (int chk = 0; chk < 4; ++chk){
    #pragma unroll
    for (int rep = 0; rep < 6; ++rep){
      int idx = tid + rep*256; int half = idx >= 768 ? 1 : 0; int i2 = idx - half*768;
      int rr = i2 >> 3, ko = (i2 & 7)*8;
      *(bf8v*)&SB[chk & 1][half][rr][ko] = pre[rep];
    }
    __syncthreads();
    if (chk < 3){
      #pragma unroll
      for (int rep = 0; rep < 6; ++rep){
        int idx = tid + rep*256; int half = idx >= 768 ? 1 : 0; int i2 = idx - half*768;
        int rr = i2 >> 3, ko = (i2 & 7)*8;
        int j = 32*s + (rr & 31) + 512*(rr >> 5);
        const __hip_bfloat16* sp = (half ? WL : WH) + (size_t)j*CINDIM;
        pre[rep] = *(const bf8v*)(sp + (chk+1)*64 + ko);
      }
    }
    #pragma unroll
    for (int sub = 0; sub < 2; ++sub){
      int kk = 2*chk + sub; int ko = 32*sub + 8*lg;
      bf8v a = A0[kk];
      #pragma unroll
      for (int nf = 0; nf < 6; ++nf){
        bf8v bh = *(const bf8v*)&SB[chk & 1][0][16*nf + l15][ko];
        bf8v bl = *(const bf8v*)&SB[chk & 1][1][16*nf + l15][ko];
        acc[nf] = mf(a, bh, acc[nf]);
        acc[nf] = mf(a, bl, acc[nf]);
      }
    }
  }

  #pragma unroll
  for (int r = 0; r < 4; ++r){
    int row = 16*w + 4*lg + r;
    float sm = 0.f, sq = 0.f;
    #pragma unroll
    for (int nf = 0; nf < 6; ++nf){
      float v = acc[nf][r];
      sm += v; sq += v*v;
      int tc = 16*nf + l15;
      int j = 32*s + (tc & 31) + 512*(tc >> 5);
      GX0[(size_t)row*THREE_H + j] = __float2bfloat16(v);
    }
    #pragma unroll
    for (int m = 1; m < 16; m <<= 1){ sm += __shfl_xor(sm, m); sq += __shfl_xor(sq, m); }
    if (l15 == 0){
      atomicAdd(&statsX[((size_t)t*64 + row)*2 + 0], sm);
      atomicAdd(&statsX[((size_t)t*64 + row)*2 + 1], sq);
    }
  }
}

// ---- K2b: finalize x stats (sum,sumsq) -> (mean, rstd) in place ----
__global__ void k_statsx(float* __restrict__ sx){
  int i = blockIdx.x*blockDim.x + threadIdx.x;
  if (i < T_STEPS*NBATCH){
    float s = sx[2*i], q = sx[2*i+1];
    float m = s * (1.0f/1536.0f);
    float v = fmaxf(q * (1.0f/1536.0f) - m*m, 0.0f);
    sx[2*i] = m;
    sx[2*i+1] = rsqrtf(v + EPSLN);
  }
}

// ---- K3: persistent recurrent kernel, 48 blocks x 256 threads ----
__global__ __launch_bounds__(256,1) void k_rnn(
    const float* __restrict__ gx0g, const float* __restrict__ gx0b,
    const float* __restrict__ gh0g, const float* __restrict__ gh0b,
    const float* __restrict__ gx1g, const float* __restrict__ gx1b,
    const float* __restrict__ gh1g, const float* __restrict__ gh1b,
    unsigned char* __restrict__ ws, float* __restrict__ out)
{
  const int tid = threadIdx.x, bi = blockIdx.x;
  const int lane = tid & 63, w = tid >> 6, l15 = lane & 15, lg = lane >> 4;

  unsigned int* flags = (unsigned int*)(ws + OFF_BAR);
  float* statsA = (float*)(ws + OFF_STATSA);                 // [2][3][64][2] raw sums
  __hip_bfloat16* h0bf = (__hip_bfloat16*)(ws + OFF_H0BF);
  __hip_bfloat16* h1bf = (__hip_bfloat16*)(ws + OFF_H1BF);
  const float* statsX = (const float*)(ws + OFF_STATSX);     // [1024][64]{mean,rstd}
  const __hip_bfloat16* GX0 = (const __hip_bfloat16*)(ws + OFF_GX0);
  const __hip_bfloat16* W0H = (const __hip_bfloat16*)(ws + OFF_WH0HI);
  const __hip_bfloat16* W0L = (const __hip_bfloat16*)(ws + OFF_WH0LO);
  const __hip_bfloat16* X1H = (const __hip_bfloat16*)(ws + OFF_WX1HI);
  const __hip_bfloat16* X1L = (const __hip_bfloat16*)(ws + OFF_WX1LO);
  const __hip_bfloat16* H1H = (const __hip_bfloat16*)(ws + OFF_WH1HI);
  const __hip_bfloat16* H1L = (const __hip_bfloat16*)(ws + OFF_WH1LO);

  __shared__ __hip_bfloat16 SB[2][2][96][72];

  const bool isL0 = (bi < 16);
  const int s16 = bi - 16;

  float PGXg[2][3], PGXb[2][3], PGHg[2][3], PGHb[2][3];  // L0
  float QXg[3], QXb[3], QHg[3], QHb[3];                  // X1
  if (isL0){
    #pragma unroll
    for (int fi = 0; fi < 2; ++fi)
      #pragma unroll
      for (int g = 0; g < 3; ++g){
        int j = 32*bi + l15 + 16*fi + 512*g;
        PGXg[fi][g] = gx0g[j]; PGXb[fi][g] = gx0b[j];
        PGHg[fi][g] = gh0g[j]; PGHb[fi][g] = gh0b[j];
      }
  } else {
    #pragma unroll
    for (int g = 0; g < 3; ++g){
      int j = 16*s16 + l15 + 512*g;
      QXg[g] = gx1g[j]; QXb[g] = gx1b[j];
      QHg[g] = gh1g[j]; QHb[g] = gh1b[j];
    }
  }

  float hp0[2][4] = {{0.f,0.f,0.f,0.f},{0.f,0.f,0.f,0.f}};
  float hp1[4] = {0.f,0.f,0.f,0.f};
  unsigned int bc = 0;   // barrier epoch

  for (int tau = 0; tau <= T_STEPS; ++tau){
    const bool act = isL0 ? (tau < T_STEPS) : (tau >= 1);
    const int p = tau & 1;

    f4 acc[6]; f4 acc1[3];
    float gxraw[2][3][4], mx[4], rsx[4];

    // -------- P1: GEMMs + stats --------
    if (act){
      #pragma unroll
      for (int i = 0; i < 6; ++i) acc[i] = f4{0.f,0.f,0.f,0.f};
      #pragma unroll
      for (int i = 0; i < 3; ++i) acc1[i] = f4{0.f,0.f,0.f,0.f};

      // A preload via MALL (device-coherent): h0 frags; h1 frags (X1 only)
      bf8v A0[16], A1[16];
      #pragma unroll
      for (int kk = 0; kk < 16; ++kk)
        A0[kk] = ld16_cross(h0bf + (16*w + l15)*HDIM + kk*32 + 8*lg);
      if (!isL0){
        #pragma unroll
        for (int kk = 0; kk < 16; ++kk)
          A1[kk] = ld16_cross(h1bf + (16*w + l15)*HDIM + kk*32 + 8*lg);
      }

      auto srcrow = [&](int rr, int half) -> const __hip_bfloat16* {
        if (isL0){
          int j = 32*bi + (rr & 31) + 512*(rr >> 5);
          return (half ? W0L : W0H) + (size_t)j*HDIM;
        }
        int r2 = (rr < 48) ? rr : (rr - 48);
        int j = 16*s16 + (r2 & 15) + 512*(r2 >> 4);
        if (rr < 48) return (half ? X1L : X1H) + (size_t)j*HDIM;
        return (half ? H1L : H1H) + (size_t)j*HDIM;
      };

      bf8v pre[6];
      #pragma unroll
      for (int rep = 0; rep < 6; ++rep){
        int idx = tid + rep*256; int half = idx >= 768 ? 1 : 0; int i2 = idx - half*768;
        int rr = i2 >> 3, ko = (i2 & 7)*8;
        pre[rep] = *(const bf8v*)(srcrow(rr, half) + ko);
      }
      // drain A-frags (asm loads: compiler doesn't track) + initial pre
      vm_drain();

      #pragma unroll
      for (int chk = 0; chk < 8; ++chk){
        #pragma unroll
        for (int rep = 0; rep < 6; ++rep){
          int idx = tid + rep*256; int half = idx >= 768 ? 1 : 0; int i2 = idx - half*768;
          int rr = i2 >> 3, ko = (i2 & 7)*8;
          *(bf8v*)&SB[chk & 1][half][rr][ko] = pre[rep];
        }
        __syncthreads();
        if (chk < 7){
          #pragma unroll
          for (int rep = 0; rep < 6; ++rep){
            int idx = tid + rep*256; int half = idx >= 768 ? 1 : 0; int i2 = idx - half*768;
            int rr = i2 >> 3, ko = (i2 & 7)*8;
            pre[rep] = *(const bf8v*)(srcrow(rr, half) + (chk+1)*64 + ko);
          }
        }
        #pragma unroll
        for (int sub = 0; sub < 2; ++sub){
          int kk = 2*chk + sub; int ko = 32*sub + 8*lg;
          if (isL0){
            bf8v a = A0[kk];
            #pragma unroll
            for (int nf = 0; nf < 6; ++nf){
              bf8v bh = *(const bf8v*)&SB[chk & 1][0][16*nf + l15][ko];
              bf8v bl = *(const bf8v*)&SB[chk & 1][1][16*nf + l15][ko];
              acc[nf] = mf(a, bh, acc[nf]);
              acc[nf] = mf(a, bl, acc[nf]);
            }
          } else {
            bf8v a0 = A0[kk], a1 = A1[kk];
            #pragma unroll
            for (int nf = 0; nf < 3; ++nf){
              bf8v bh = *(const bf8v*)&SB[chk & 1][0][16*nf + l15][ko];
              bf8v bl = *(const bf8v*)&SB[chk & 1][1][16*nf + l15][ko];
              acc[nf] = mf(a0, bh, acc[nf]);
              acc[nf] = mf(a0, bl, acc[nf]);
              bf8v ch2 = *(const bf8v*)&SB[chk & 1][0][48 + 16*nf + l15][ko];
              bf8v cl2 = *(const bf8v*)&SB[chk & 1][1][48 + 16*nf + l15][ko];
              acc1[nf] = mf(a1, ch2, acc1[nf]);
              acc1[nf] = mf(a1, cl2, acc1[nf]);
            }
          }
        }
      }

      // L0: x-gate raw values + stats for this step (plain cached loads,
      // issued here so they overlap with stat atomics + B1 wait)
      if (isL0){
        #pragma unroll
        for (int r = 0; r < 4; ++r){
          int row = 16*w + 4*lg + r;
          mx[r]  = statsX[((size_t)tau*64 + row)*2 + 0];
          rsx[r] = statsX[((size_t)tau*64 + row)*2 + 1];
          #pragma unroll
          for (int fi = 0; fi < 2; ++fi)
            #pragma unroll
            for (int g = 0; g < 3; ++g)
              gxraw[fi][g][r] = __bfloat162float(
                GX0[(size_t)tau*(NBATCH*THREE_H) + (size_t)row*THREE_H
                    + (32*bi + l15 + 16*fi + 512*g)]);
        }
      }

      // row-stat atomics (agent scope -> MALL), parity p
      if (isL0){
        float* st0 = statsA + ((size_t)p*3 + 0)*64*2;
        #pragma unroll
        for (int r = 0; r < 4; ++r){
          float sm = 0.f, sq = 0.f;
          #pragma unroll
          for (int nf = 0; nf < 6; ++nf){ float v = acc[nf][r]; sm += v; sq += v*v; }
          #pragma unroll
          for (int m = 1; m < 16; m <<= 1){ sm += __shfl_xor(sm, m); sq += __shfl_xor(sq, m); }
          if (l15 == 0){
            int row = 16*w + 4*lg + r;
            atomicAdd(&st0[row*2 + 0], sm);
            atomicAdd(&st0[row*2 + 1], sq);
          }
        }
      } else {
        float* st1 = statsA + ((size_t)p*3 + 1)*64*2;
        float* st2 = statsA + ((size_t)p*3 + 2)*64*2;
        #pragma unroll
        for (int r = 0; r < 4; ++r){
          float s1 = 0.f, q1 = 0.f, s2 = 0.f, q2 = 0.f;
          #pragma unroll
          for (int nf = 0; nf < 3; ++nf){
            float v = acc[nf][r];  s1 += v; q1 += v*v;
            float u = acc1[nf][r]; s2 += u; q2 += u*u;
          }
          #pragma unroll
          for (int m = 1; m < 16; m <<= 1){
            s1 += __shfl_xor(s1, m); q1 += __shfl_xor(q1, m);
            s2 += __shfl_xor(s2, m); q2 += __shfl_xor(q2, m);
          }
          if (l15 == 0){
            int row = 16*w + 4*lg + r;
            atomicAdd(&st1[row*2 + 0], s1); atomicAdd(&st1[row*2 + 1], q1);
            atomicAdd(&st2[row*2 + 0], s2); atomicAdd(&st2[row*2 + 1], q2);
          }
        }
      }
    }

    gbar(flags, ++bc);   // B1: stats complete

    // -------- P2: combine --------
    if (act){
      if (isL0){
        const float* st0 = statsA + ((size_t)p*3 + 0)*64*2;
        f2 sp4[4];
        #pragma unroll
        for (int r = 0; r < 4; ++r){
          int row = 16*w + 4*lg + r;
          sp4[r] = ld8_cross(st0 + row*2);
        }
        vm_drain();
        #pragma unroll
        for (int r = 0; r < 4; ++r){
          int row = 16*w + 4*lg + r;
          float m  = sp4[r][0] * (1.0f/1536.0f);
          float vv = fmaxf(sp4[r][1] * (1.0f/1536.0f) - m*m, 0.0f);
          float rs = rsqrtf(vv + EPSLN);
          #pragma unroll
          for (int fi = 0; fi < 2; ++fi){
            float zr = acc[fi][r], zi = acc[2+fi][r], zn = acc[4+fi][r];
            float ghr = (zr - m)*rs*PGHg[fi][0] + PGHb[fi][0];
            float ghi = (zi - m)*rs*PGHg[fi][1] + PGHb[fi][1];
            float ghn = (zn - m)*rs*PGHg[fi][2] + PGHb[fi][2];
            float gxr = (gxraw[fi][0][r] - mx[r])*rsx[r]*PGXg[fi][0] + PGXb[fi][0];
            float gxi = (gxraw[fi][1][r] - mx[r])*rsx[r]*PGXg[fi][1] + PGXb[fi][1];
            float gxn = (gxraw[fi][2][r] - mx[r])*rsx[r]*PGXg[fi][2] + PGXb[fi][2];
            float rg = sigf(gxr + ghr);
            float ig = sigf(gxi + ghi);
            float nn = tanhfast(gxn + rg*ghn);
            float hn = nn + ig*(hp0[fi][r] - nn);
            hp0[fi][r] = hn;
            __hip_bfloat16 hb = __float2bfloat16(hn);
            st2_cross(h0bf + row*HDIM + 32*bi + l15 + 16*fi,
                      (unsigned int)*reinterpret_cast<unsigned short*>(&hb));
          }
        }
      } else {
        const int t1 = tau - 1;
        const float* st1 = statsA + ((size_t)p*3 + 1)*64*2;
        const float* st2 = statsA + ((size_t)p*3 + 2)*64*2;
        f2 s1p[4], s2p[4];
        #pragma unroll
        for (int r = 0; r < 4; ++r){
          int row = 16*w + 4*lg + r;
          s1p[r] = ld8_cross(st1 + row*2);
          s2p[r] = ld8_cross(st2 + row*2);
        }
        vm_drain();
        #pragma unroll
        for (int r = 0; r < 4; ++r){
          int row = 16*w + 4*lg + r;
          float m1 = s1p[r][0]*(1.0f/1536.0f);
          float v1 = fmaxf(s1p[r][1]*(1.0f/1536.0f) - m1*m1, 0.0f);
          float rs1 = rsqrtf(v1 + EPSLN);
          float m2 = s2p[r][0]*(1.0f/1536.0f);
          float v2 = fmaxf(s2p[r][1]*(1.0f/1536.0f) - m2*m2, 0.0f);
          float rs2 = rsqrtf(v2 + EPSLN);
          float gxr = (acc[0][r] - m1)*rs1*QXg[0] + QXb[0];
          float gxi = (acc[1][r] - m1)*rs1*QXg[1] + QXb[1];
          float gxn = (acc[2][r] - m1)*rs1*QXg[2] + QXb[2];
          float ghr = (acc1[0][r] - m2)*rs2*QHg[0] + QHb[0];
          float ghi = (acc1[1][r] - m2)*rs2*QHg[1] + QHb[1];
          float ghn = (acc1[2][r] - m2)*rs2*QHg[2] + QHb[2];
          float rg = sigf(gxr + ghr);
          float ig = sigf(gxi + ghi);
          float nn = tanhfast(gxn + rg*ghn);
          float hn = nn + ig*(hp1[r] - nn);
          hp1[r] = hn;
          int j = 16*s16 + l15;
          __hip_bfloat16 hb = __float2bfloat16(hn);
          st2_cross(h1bf + row*HDIM + j,
                    (unsigned int)*reinterpret_cast<unsigned short*>(&hb));
          out[(size_t)row*(HDIM*T_STEPS) + (size_t)j*T_STEPS + t1] = hn;
        }
      }
    }
    // block 0 zeroes the other-parity stat accumulators for step tau+1
    if (bi == 0){
      float* dst = statsA + (size_t)(p ^ 1)*3*64*2;
      for (int i = tid; i < 384; i += 256) st4_cross(&dst[i], 0.f);
    }

    gbar(flags, ++bc);   // B2: h published
  }
}

// ---------------------------------------------------------------------------
extern "C" void kernel_launch(void* const* d_in, const int* in_sizes, int n_in,
                              void* d_out, int out_size, void* d_ws, size_t ws_size,
                              hipStream_t stream) {
  const float* xs  = (const float*)d_in[0];
  const float* Wx0 = (const float*)d_in[1];
  const float* Wh0 = (const float*)d_in[2];
  const float* gx0g = (const float*)d_in[3];
  const float* gx0b = (const float*)d_in[4];
  const float* gh0g = (const float*)d_in[5];
  const float* gh0b = (const float*)d_in[6];
  const float* Wx1 = (const float*)d_in[7];
  const float* Wh1 = (const float*)d_in[8];
  const float* gx1g = (const float*)d_in[9];
  const float* gx1b = (const float*)d_in[10];
  const float* gh1g = (const float*)d_in[11];
  const float* gh1b = (const float*)d_in[12];

  unsigned char* ws = (unsigned char*)d_ws;
  float* out = (float*)d_out;
  (void)in_sizes; (void)n_in; (void)out_size; (void)ws_size;

  // K0: zero flags + statsA + h0bf + h1bf + statsX (head region)
  k_zero<<<256, 256, 0, stream>>>((unsigned int*)ws, (int)(OFF_WH0HI/4));

  // K1: weight hi/lo conversion
  k_conv<<<512, 256, 0, stream>>>(Wh0, (__hip_bfloat16*)(ws+OFF_WH0HI), (__hip_bfloat16*)(ws+OFF_WH0LO), THREE_H*HDIM);
  k_conv<<<512, 256, 0, stream>>>(Wx1, (__hip_bfloat16*)(ws+OFF_WX1HI), (__hip_bfloat16*)(ws+OFF_WX1LO), THREE_H*HDIM);
  k_conv<<<512, 256, 0, stream>>>(Wh1, (__hip_bfloat16*)(ws+OFF_WH1HI), (__hip_bfloat16*)(ws+OFF_WH1LO), THREE_H*HDIM);
  k_conv<<<512, 256, 0, stream>>>(Wx0, (__hip_bfloat16*)(ws+OFF_WX0HI), (__hip_bfloat16*)(ws+OFF_WX0LO), THREE_H*CINDIM);

  // K1b: xs transpose -> xsT bf16
  k_tr<<<4096, 256, 0, stream>>>(xs, (__hip_bfloat16*)(ws+OFF_XST));

  // K2: x-path GEMM for all timesteps (raw z + stat sums)
  k_xgemm<<<16384, 256, 0, stream>>>(ws);

  // K2b: finalize x stats
  k_statsx<<<256, 256, 0, stream>>>((float*)(ws+OFF_STATSX));

  // K3: persistent recurrence
  k_rnn<<<NBLK, 256, 0, stream>>>(gx0g, gx0b, gh0g, gh0b, gx1g, gx1b, gh1g, gh1b, ws, out);
}

// Round 4
// 18650.743 us; speedup vs baseline: 2.0212x; 1.2289x over previous
//
#include <hip/hip_runtime.h>
#include <hip/hip_bf16.h>
#include <cstdint>
#include <cstddef>

// ---------------------------------------------------------------------------
// StackedLayerNormGRU  (B=64, C_IN=256, H=512, T=1024)
//
// Round 4: R2 shell (48 persistent blocks, 2 distributed-flag barriers/step,
// sc0 sc1 for all cross-block data) with ONE change: stat atomics replaced by
// per-block partial stores + post-B1 tree reduce (no atomics in steady state).
// ---------------------------------------------------------------------------

#define NBATCH 64
#define HDIM   512
#define THREE_H 1536
#define CINDIM 256
#define T_STEPS 1024
#define EPSLN 1e-5f
#define NBLK 48   // 16 L0 blocks + 32 X1 blocks

typedef __bf16 bf8v __attribute__((ext_vector_type(8)));
typedef float f4 __attribute__((ext_vector_type(4)));
typedef float f2 __attribute__((ext_vector_type(2)));
typedef unsigned int u32x4 __attribute__((ext_vector_type(4)));

// ---- workspace layout (bytes) ----
static constexpr size_t OFF_BAR    = 0;          // 48 flags x 128B
static constexpr size_t OFF_ST0P   = 8192;       // [64][16][2] f32 = 8192
static constexpr size_t OFF_ST1P   = 16384;      // [64][32][2] f32 = 16384
static constexpr size_t OFF_ST2P   = 32768;      // [64][32][2] f32 = 16384
static constexpr size_t OFF_H0BF   = 49152;      // 64*512 bf16 = 65536
static constexpr size_t OFF_H1BF   = 114688;     // 65536
static constexpr size_t OFF_STATSX = 180224;     // [1024][64][2] f32 = 524288
static constexpr size_t OFF_WH0HI  = 704512;     // 1536*512 bf16 = 1572864 each
static constexpr size_t OFF_WH0LO  = OFF_WH0HI + 1572864;
static constexpr size_t OFF_WX1HI  = OFF_WH0LO + 1572864;
static constexpr size_t OFF_WX1LO  = OFF_WX1HI + 1572864;
static constexpr size_t OFF_WH1HI  = OFF_WX1LO + 1572864;
static constexpr size_t OFF_WH1LO  = OFF_WH1HI + 1572864;
static constexpr size_t OFF_WX0HI  = OFF_WH1LO + 1572864;   // 1536*256 bf16
static constexpr size_t OFF_WX0LO  = OFF_WX0HI + 786432;
static constexpr size_t OFF_XST    = OFF_WX0LO + 786432;    // 33554432
static constexpr size_t OFF_GX0    = OFF_XST + 33554432;    // 201326592

__device__ __forceinline__ f4 mf(bf8v a, bf8v b, f4 c){
  return __builtin_amdgcn_mfma_f32_16x16x32_bf16(a, b, c, 0, 0, 0);
}
__device__ __forceinline__ float sigf(float x){ return 1.0f/(1.0f + __expf(-x)); }
__device__ __forceinline__ float tanhfast(float x){ return 1.0f - 2.0f/(__expf(2.0f*x) + 1.0f); }

// ---- device-coherent (MALL) access helpers ----
__device__ __forceinline__ bf8v ld16_cross(const void* p){
  u32x4 t;
  asm volatile("global_load_dwordx4 %0, %1, off sc0 sc1" : "=v"(t) : "v"(p));
  return __builtin_bit_cast(bf8v, t);
}
__device__ __forceinline__ f4 ld16f_cross(const float* p){
  f4 v;
  asm volatile("global_load_dwordx4 %0, %1, off sc0 sc1" : "=v"(v) : "v"(p));
  return v;
}
__device__ __forceinline__ void st2_cross(__hip_bfloat16* p, unsigned int u){
  asm volatile("global_store_short %0, %1, off sc0 sc1" :: "v"(p), "v"(u));
}
__device__ __forceinline__ void st8f_cross(float* p, f2 v){
  asm volatile("global_store_dwordx2 %0, %1, off sc0 sc1" :: "v"(p), "v"(v));
}
__device__ __forceinline__ void vm_drain(){
  asm volatile("s_waitcnt vmcnt(0)" ::: "memory");
  __builtin_amdgcn_sched_barrier(0);
}

// ---- distributed flag barrier: 48 flags, 128B apart, epoch-numbered ----
__device__ __forceinline__ void gbar(unsigned int* flags, unsigned int target){
  asm volatile("s_waitcnt vmcnt(0) lgkmcnt(0)" ::: "memory");
  __syncthreads();
  if (threadIdx.x == 0){
    unsigned int* myf = flags + (size_t)blockIdx.x * 32;
    asm volatile("global_store_dword %0, %1, off sc0 sc1" :: "v"(myf), "v"(target) : "memory");
  }
  const int lane = threadIdx.x & 63;
  const unsigned int* pf = flags + (size_t)lane * 32;
  for (;;){
    unsigned int v = target;
    if (lane < NBLK){
      asm volatile("global_load_dword %0, %1, off sc0 sc1\n\ts_waitcnt vmcnt(0)"
                   : "=v"(v) : "v"(pf) : "memory");
    }
    if (__all((int)(v >= target))) break;
    __builtin_amdgcn_s_sleep(1);
  }
}

// ---- K0: zero head of workspace ----
__global__ void k_zero(unsigned int* p, int nwords){
  for (int i = blockIdx.x*blockDim.x + threadIdx.x; i < nwords; i += gridDim.x*blockDim.x)
    p[i] = 0u;
}

// ---- K1: fp32 weight -> bf16 hi/lo split ----
__global__ void k_conv(const float* __restrict__ src, __hip_bfloat16* __restrict__ hi,
                       __hip_bfloat16* __restrict__ lo, int n){
  for (int i = blockIdx.x*blockDim.x + threadIdx.x; i < n; i += gridDim.x*blockDim.x){
    float w = src[i];
    __hip_bfloat16 h = __float2bfloat16(w);
    hi[i] = h;
    lo[i] = __float2bfloat16(w - __bfloat162float(h));
  }
}

// ---- K1b: xs [B][C][T] f32 -> xsT [T][B][C] bf16 ----
__global__ void k_tr(const float* __restrict__ xs, __hip_bfloat16* __restrict__ xsT){
  const int total = NBATCH * CINDIM * (T_STEPS/4);
  for (int idx = blockIdx.x*blockDim.x + threadIdx.x; idx < total; idx += gridDim.x*blockDim.x){
    int b  = idx >> 16;
    int c  = (idx >> 8) & 255;
    int t4 = idx & 255;
    const float4 v = *(const float4*)(xs + ((size_t)b*CINDIM + c)*T_STEPS + t4*4);
    float vv[4] = {v.x, v.y, v.z, v.w};
    #pragma unroll
    for (int i = 0; i < 4; ++i)
      xsT[(size_t)(4*t4 + i)*(NBATCH*CINDIM) + b*CINDIM + c] = __float2bfloat16(vv[i]);
  }
}

// ---- K2: gate_x0 raw GEMM + stat atomics (parallel phase; atomics OK here) ----
__global__ __launch_bounds__(256,1) void k_xgemm(unsigned char* __restrict__ ws){
  const int tid = threadIdx.x;
  const int bx = blockIdx.x;
  const int t = bx >> 4, s = bx & 15;
  const int lane = tid & 63, w = tid >> 6, l15 = lane & 15, lg = lane >> 4;

  const __hip_bfloat16* X  = (const __hip_bfloat16*)(ws + OFF_XST) + (size_t)t*(NBATCH*CINDIM);
  const __hip_bfloat16* WH = (const __hip_bfloat16*)(ws + OFF_WX0HI);
  const __hip_bfloat16* WL = (const __hip_bfloat16*)(ws + OFF_WX0LO);
  float* statsX = (float*)(ws + OFF_STATSX);
  __hip_bfloat16* GX0 = (__hip_bfloat16*)(ws + OFF_GX0) + (size_t)t*(NBATCH*THREE_H);

  __shared__ __hip_bfloat16 SB[2][2][96][72];

  f4 acc[6];
  #pragma unroll
  for (int i = 0; i < 6; ++i) acc[i] = f4{0.f,0.f,0.f,0.f};

  bf8v A0[8];
  #pragma unroll
  for (int kk = 0; kk < 8; ++kk)
    A0[kk] = *(const bf8v*)(X + (16*w + l15)*CINDIM + kk*32 + 8*lg);

  bf8v pre[6];
  #pragma unroll
  for (int rep = 0; rep < 6; ++rep){
    int idx = tid + rep*256; int half = idx >= 768 ? 1 : 0; int i2 = idx - half*768;
    int rr = i2 >> 3, ko = (i2 & 7)*8;
    int j = 32*s + (rr & 31) + 512*(rr >> 5);
    const __hip_bfloat16* sp = (half ? WL : WH) + (size_t)j*CINDIM;
    pre[rep] = *(const bf8v*)(sp + ko);
  }
  #pragma unroll
  for (int chk = 0; chk < 4; ++chk){
    #pragma unroll
    for (int rep = 0; rep < 6; ++rep){
      int idx = tid + rep*256; int half = idx >= 768 ? 1 : 0; int i2 = idx - half*768;
      int rr = i2 >> 3, ko = (i2 & 7)*8;
      *(bf8v*)&SB[chk & 1][half][rr][ko] = pre[rep];
    }
    __syncthreads();
    if (chk < 3){
      #pragma unroll
      for (int rep = 0; rep < 6; ++rep){
        int idx = tid + rep*256; int half = idx >= 768 ? 1 : 0; int i2 = idx - half*768;
        int rr = i2 >> 3, ko = (i2 & 7)*8;
        int j = 32*s + (rr & 31) + 512*(rr >> 5);
        const __hip_bfloat16* sp = (half ? WL : WH) + (size_t)j*CINDIM;
        pre[rep] = *(const bf8v*)(sp + (chk+1)*64 + ko);
      }
    }
    #pragma unroll
    for (int sub = 0; sub < 2; ++sub){
      int kk = 2*chk + sub; int ko = 32*sub + 8*lg;
      bf8v a = A0[kk];
      #pragma unroll
      for (int nf = 0; nf < 6; ++nf){
        bf8v bh = *(const bf8v*)&SB[chk & 1][0][16*nf + l15][ko];
        bf8v bl = *(const bf8v*)&SB[chk & 1][1][16*nf + l15][ko];
        acc[nf] = mf(a, bh, acc[nf]);
        acc[nf] = mf(a, bl, acc[nf]);
      }
    }
  }

  #pragma unroll
  for (int r = 0; r < 4; ++r){
    int row = 16*w + 4*lg + r;
    float sm = 0.f, sq = 0.f;
    #pragma unroll
    for (int nf = 0; nf < 6; ++nf){
      float v = acc[nf][r];
      sm += v; sq += v*v;
      int tc = 16*nf + l15;
      int j = 32*s + (tc & 31) + 512*(tc >> 5);
      GX0[(size_t)row*THREE_H + j] = __float2bfloat16(v);
    }
    #pragma unroll
    for (int m = 1; m < 16; m <<= 1){ sm += __shfl_xor(sm, m); sq += __shfl_xor(sq, m); }
    if (l15 == 0){
      atomicAdd(&statsX[((size_t)t*64 + row)*2 + 0], sm);
      atomicAdd(&statsX[((size_t)t*64 + row)*2 + 1], sq);
    }
  }
}

// ---- K2b: finalize x stats ----
__global__ void k_statsx(float* __restrict__ sx){
  int i = blockIdx.x*blockDim.x + threadIdx.x;
  if (i < T_STEPS*NBATCH){
    float s = sx[2*i], q = sx[2*i+1];
    float m = s * (1.0f/1536.0f);
    float v = fmaxf(q * (1.0f/1536.0f) - m*m, 0.0f);
    sx[2*i] = m;
    sx[2*i+1] = rsqrtf(v + EPSLN);
  }
}

// ---- K3: persistent recurrent kernel, 48 blocks x 256 threads ----
__global__ __launch_bounds__(256,1) void k_rnn(
    const float* __restrict__ gx0g, const float* __restrict__ gx0b,
    const float* __restrict__ gh0g, const float* __restrict__ gh0b,
    const float* __restrict__ gx1g, const float* __restrict__ gx1b,
    const float* __restrict__ gh1g, const float* __restrict__ gh1b,
    unsigned char* __restrict__ ws, float* __restrict__ out)
{
  const int tid = threadIdx.x, bi = blockIdx.x;
  const int lane = tid & 63, w = tid >> 6, l15 = lane & 15, lg = lane >> 4;

  unsigned int* flags = (unsigned int*)(ws + OFF_BAR);
  float* st0P = (float*)(ws + OFF_ST0P);   // [64][16][2] partial sums
  float* st1P = (float*)(ws + OFF_ST1P);   // [64][32][2]
  float* st2P = (float*)(ws + OFF_ST2P);   // [64][32][2]
  __hip_bfloat16* h0bf = (__hip_bfloat16*)(ws + OFF_H0BF);
  __hip_bfloat16* h1bf = (__hip_bfloat16*)(ws + OFF_H1BF);
  const float* statsX = (const float*)(ws + OFF_STATSX);
  const __hip_bfloat16* GX0 = (const __hip_bfloat16*)(ws + OFF_GX0);
  const __hip_bfloat16* W0H = (const __hip_bfloat16*)(ws + OFF_WH0HI);
  const __hip_bfloat16* W0L = (const __hip_bfloat16*)(ws + OFF_WH0LO);
  const __hip_bfloat16* X1H = (const __hip_bfloat16*)(ws + OFF_WX1HI);
  const __hip_bfloat16* X1L = (const __hip_bfloat16*)(ws + OFF_WX1LO);
  const __hip_bfloat16* H1H = (const __hip_bfloat16*)(ws + OFF_WH1HI);
  const __hip_bfloat16* H1L = (const __hip_bfloat16*)(ws + OFF_WH1LO);

  __shared__ __hip_bfloat16 SB[2][2][96][72];
  __shared__ f2 BC0[64];
  __shared__ f2 BC1[64];
  __shared__ f2 BC2[64];

  const bool isL0 = (bi < 16);
  const int s16 = bi - 16;

  float PGXg[2][3], PGXb[2][3], PGHg[2][3], PGHb[2][3];  // L0
  float QXg[3], QXb[3], QHg[3], QHb[3];                  // X1
  if (isL0){
    #pragma unroll
    for (int fi = 0; fi < 2; ++fi)
      #pragma unroll
      for (int g = 0; g < 3; ++g){
        int j = 32*bi + l15 + 16*fi + 512*g;
        PGXg[fi][g] = gx0g[j]; PGXb[fi][g] = gx0b[j];
        PGHg[fi][g] = gh0g[j]; PGHb[fi][g] = gh0b[j];
      }
  } else {
    #pragma unroll
    for (int g = 0; g < 3; ++g){
      int j = 16*s16 + l15 + 512*g;
      QXg[g] = gx1g[j]; QXb[g] = gx1b[j];
      QHg[g] = gh1g[j]; QHb[g] = gh1b[j];
    }
  }

  float hp0[2][4] = {{0.f,0.f,0.f,0.f},{0.f,0.f,0.f,0.f}};
  float hp1[4] = {0.f,0.f,0.f,0.f};
  unsigned int bc = 0;

  for (int tau = 0; tau <= T_STEPS; ++tau){
    const bool act = isL0 ? (tau < T_STEPS) : (tau >= 1);

    f4 acc[6]; f4 acc1[3];
    float gxraw[2][3][4], mx[4], rsx[4];

    // -------- P1: GEMMs + stat partial stores --------
    if (act){
      #pragma unroll
      for (int i = 0; i < 6; ++i) acc[i] = f4{0.f,0.f,0.f,0.f};
      #pragma unroll
      for (int i = 0; i < 3; ++i) acc1[i] = f4{0.f,0.f,0.f,0.f};

      bf8v A0[16], A1[16];
      #pragma unroll
      for (int kk = 0; kk < 16; ++kk)
        A0[kk] = ld16_cross(h0bf + (16*w + l15)*HDIM + kk*32 + 8*lg);
      if (!isL0){
        #pragma unroll
        for (int kk = 0; kk < 16; ++kk)
          A1[kk] = ld16_cross(h1bf + (16*w + l15)*HDIM + kk*32 + 8*lg);
      }

      auto srcrow = [&](int rr, int half) -> const __hip_bfloat16* {
        if (isL0){
          int j = 32*bi + (rr & 31) + 512*(rr >> 5);
          return (half ? W0L : W0H) + (size_t)j*HDIM;
        }
        int r2 = (rr < 48) ? rr : (rr - 48);
        int j = 16*s16 + (r2 & 15) + 512*(r2 >> 4);
        if (rr < 48) return (half ? X1L : X1H) + (size_t)j*HDIM;
        return (half ? H1L : H1H) + (size_t)j*HDIM;
      };

      bf8v pre[6];
      #pragma unroll
      for (int rep = 0; rep < 6; ++rep){
        int idx = tid + rep*256; int half = idx >= 768 ? 1 : 0; int i2 = idx - half*768;
        int rr = i2 >> 3, ko = (i2 & 7)*8;
        pre[rep] = *(const bf8v*)(srcrow(rr, half) + ko);
      }
      vm_drain();

      #pragma unroll
      for (int chk = 0; chk < 8; ++chk){
        #pragma unroll
        for (int rep = 0; rep < 6; ++rep){
          int idx = tid + rep*256; int half = idx >= 768 ? 1 : 0; int i2 = idx - half*768;
          int rr = i2 >> 3, ko = (i2 & 7)*8;
          *(bf8v*)&SB[chk & 1][half][rr][ko] = pre[rep];
        }
        __syncthreads();
        if (chk < 7){
          #pragma unroll
          for (int rep = 0; rep < 6; ++rep){
            int idx = tid + rep*256; int half = idx >= 768 ? 1 : 0; int i2 = idx - half*768;
            int rr = i2 >> 3, ko = (i2 & 7)*8;
            pre[rep] = *(const bf8v*)(srcrow(rr, half) + (chk+1)*64 + ko);
          }
        }
        #pragma unroll
        for (int sub = 0; sub < 2; ++sub){
          int kk = 2*chk + sub; int ko = 32*sub + 8*lg;
          if (isL0){
            bf8v a = A0[kk];
            #pragma unroll
            for (int nf = 0; nf < 6; ++nf){
              bf8v bh = *(const bf8v*)&SB[chk & 1][0][16*nf + l15][ko];
              bf8v bl = *(const bf8v*)&SB[chk & 1][1][16*nf + l15][ko];
              acc[nf] = mf(a, bh, acc[nf]);
              acc[nf] = mf(a, bl, acc[nf]);
            }
          } else {
            bf8v a0 = A0[kk], a1 = A1[kk];
            #pragma unroll
            for (int nf = 0; nf < 3; ++nf){
              bf8v bh = *(const bf8v*)&SB[chk & 1][0][16*nf + l15][ko];
              bf8v bl = *(const bf8v*)&SB[chk & 1][1][16*nf + l15][ko];
              acc[nf] = mf(a0, bh, acc[nf]);
              acc[nf] = mf(a0, bl, acc[nf]);
              bf8v ch2 = *(const bf8v*)&SB[chk & 1][0][48 + 16*nf + l15][ko];
              bf8v cl2 = *(const bf8v*)&SB[chk & 1][1][48 + 16*nf + l15][ko];
              acc1[nf] = mf(a1, ch2, acc1[nf]);
              acc1[nf] = mf(a1, cl2, acc1[nf]);
            }
          }
        }
      }

      // L0: x-gate prefetch (plain cached loads; consumed post-B1)
      if (isL0){
        #pragma unroll
        for (int r = 0; r < 4; ++r){
          int row = 16*w + 4*lg + r;
          mx[r]  = statsX[((size_t)tau*64 + row)*2 + 0];
          rsx[r] = statsX[((size_t)tau*64 + row)*2 + 1];
          #pragma unroll
          for (int fi = 0; fi < 2; ++fi)
            #pragma unroll
            for (int g = 0; g < 3; ++g)
              gxraw[fi][g][r] = __bfloat162float(
                GX0[(size_t)tau*(NBATCH*THREE_H) + (size_t)row*THREE_H
                    + (32*bi + l15 + 16*fi + 512*g)]);
        }
      }

      // stat partial stores (NO atomics)
      if (isL0){
        #pragma unroll
        for (int r = 0; r < 4; ++r){
          float sm = 0.f, sq = 0.f;
          #pragma unroll
          for (int nf = 0; nf < 6; ++nf){ float v = acc[nf][r]; sm += v; sq += v*v; }
          #pragma unroll
          for (int m = 1; m < 16; m <<= 1){ sm += __shfl_xor(sm, m); sq += __shfl_xor(sq, m); }
          if (l15 == 0){
            int row = 16*w + 4*lg + r;
            st8f_cross(st0P + ((size_t)row*16 + bi)*2, f2{sm, sq});
          }
        }
      } else {
        #pragma unroll
        for (int r = 0; r < 4; ++r){
          float s1 = 0.f, q1 = 0.f, s2 = 0.f, q2 = 0.f;
          #pragma unroll
          for (int nf = 0; nf < 3; ++nf){
            float v = acc[nf][r];  s1 += v; q1 += v*v;
            float u = acc1[nf][r]; s2 += u; q2 += u*u;
          }
          #pragma unroll
          for (int m = 1; m < 16; m <<= 1){
            s1 += __shfl_xor(s1, m); q1 += __shfl_xor(q1, m);
            s2 += __shfl_xor(s2, m); q2 += __shfl_xor(q2, m);
          }
          if (l15 == 0){
            int row = 16*w + 4*lg + r;
            st8f_cross(st1P + ((size_t)row*32 + s16)*2, f2{s1, q1});
            st8f_cross(st2P + ((size_t)row*32 + s16)*2, f2{s2, q2});
          }
        }
      }
    }

    gbar(flags, ++bc);   // B1: partials visible

    // -------- P2: tree reduce + combine --------
    if (act){
      if (isL0){
        // reduce 16 partials/row: 4 threads per row, 2 f4 each
        {
          int row = tid >> 2, q = tid & 3;
          const float* bp = st0P + (size_t)row*32 + q*8;
          f4 v0 = ld16f_cross(bp), v1 = ld16f_cross(bp + 4);
          vm_drain();
          float s = v0[0]+v0[2]+v1[0]+v1[2];
          float qq = v0[1]+v0[3]+v1[1]+v1[3];
          s += __shfl_xor(s,1); qq += __shfl_xor(qq,1);
          s += __shfl_xor(s,2); qq += __shfl_xor(qq,2);
          if (q == 0){
            float m = s*(1.0f/1536.0f);
            float vv = fmaxf(qq*(1.0f/1536.0f) - m*m, 0.0f);
            BC0[row] = f2{m, rsqrtf(vv + EPSLN)};
          }
        }
        __syncthreads();
        #pragma unroll
        for (int r = 0; r < 4; ++r){
          int row = 16*w + 4*lg + r;
          f2 mr = BC0[row];
          float m = mr[0], rs = mr[1];
          #pragma unroll
          for (int fi = 0; fi < 2; ++fi){
            float zr = acc[fi][r], zi = acc[2+fi][r], zn = acc[4+fi][r];
            float ghr = (zr - m)*rs*PGHg[fi][0] + PGHb[fi][0];
            float ghi = (zi - m)*rs*PGHg[fi][1] + PGHb[fi][1];
            float ghn = (zn - m)*rs*PGHg[fi][2] + PGHb[fi][2];
            float gxr = (gxraw[fi][0][r] - mx[r])*rsx[r]*PGXg[fi][0] + PGXb[fi][0];
            float gxi = (gxraw[fi][1][r] - mx[r])*rsx[r]*PGXg[fi][1] + PGXb[fi][1];
            float gxn = (gxraw[fi][2][r] - mx[r])*rsx[r]*PGXg[fi][2] + PGXb[fi][2];
            float rg = sigf(gxr + ghr);
            float ig = sigf(gxi + ghi);
            float nn = tanhfast(gxn + rg*ghn);
            float hn = nn + ig*(hp0[fi][r] - nn);
            hp0[fi][r] = hn;
            __hip_bfloat16 hb = __float2bfloat16(hn);
            st2_cross(h0bf + row*HDIM + 32*bi + l15 + 16*fi,
                      (unsigned int)*reinterpret_cast<unsigned short*>(&hb));
          }
        }
      } else {
        const int t1 = tau - 1;
        // reduce 32 partials/row for st1 and st2: 4 threads/row, 4 f4 each
        {
          int row = tid >> 2, q = tid & 3;
          const float* b1 = st1P + (size_t)row*64 + q*16;
          const float* b2 = st2P + (size_t)row*64 + q*16;
          f4 a0 = ld16f_cross(b1),   a1c = ld16f_cross(b1+4);
          f4 a2 = ld16f_cross(b1+8), a3 = ld16f_cross(b1+12);
          f4 c0 = ld16f_cross(b2),   c1 = ld16f_cross(b2+4);
          f4 c2 = ld16f_cross(b2+8), c3 = ld16f_cross(b2+12);
          vm_drain();
          float s1 = a0[0]+a0[2]+a1c[0]+a1c[2]+a2[0]+a2[2]+a3[0]+a3[2];
          float q1 = a0[1]+a0[3]+a1c[1]+a1c[3]+a2[1]+a2[3]+a3[1]+a3[3];
          float s2 = c0[0]+c0[2]+c1[0]+c1[2]+c2[0]+c2[2]+c3[0]+c3[2];
          float q2 = c0[1]+c0[3]+c1[1]+c1[3]+c2[1]+c2[3]+c3[1]+c3[3];
          s1 += __shfl_xor(s1,1); q1 += __shfl_xor(q1,1);
          s1 += __shfl_xor(s1,2); q1 += __shfl_xor(q1,2);
          s2 += __shfl_xor(s2,1); q2 += __shfl_xor(q2,1);
          s2 += __shfl_xor(s2,2); q2 += __shfl_xor(q2,2);
          if (q == 0){
            float m1 = s1*(1.0f/1536.0f);
            float v1 = fmaxf(q1*(1.0f/1536.0f) - m1*m1, 0.0f);
            BC1[row] = f2{m1, rsqrtf(v1 + EPSLN)};
            float m2 = s2*(1.0f/1536.0f);
            float v2 = fmaxf(q2*(1.0f/1536.0f) - m2*m2, 0.0f);
            BC2[row] = f2{m2, rsqrtf(v2 + EPSLN)};
          }
        }
        __syncthreads();
        #pragma unroll
        for (int r = 0; r < 4; ++r){
          int row = 16*w + 4*lg + r;
          f2 m1 = BC1[row], m2 = BC2[row];
          float gxr = (acc[0][r] - m1[0])*m1[1]*QXg[0] + QXb[0];
          float gxi = (acc[1][r] - m1[0])*m1[1]*QXg[1] + QXb[1];
          float gxn = (acc[2][r] - m1[0])*m1[1]*QXg[2] + QXb[2];
          float ghr = (acc1[0][r] - m2[0])*m2[1]*QHg[0] + QHb[0];
          float ghi = (acc1[1][r] - m2[0])*m2[1]*QHg[1] + QHb[1];
          float ghn = (acc1[2][r] - m2[0])*m2[1]*QHg[2] + QHb[2];
          float rg = sigf(gxr + ghr);
          float ig = sigf(gxi + ghi);
          float nn = tanhfast(gxn + rg*ghn);
          float hn = nn + ig*(hp1[r] - nn);
          hp1[r] = hn;
          int j = 16*s16 + l15;
          __hip_bfloat16 hb = __float2bfloat16(hn);
          st2_cross(h1bf + row*HDIM + j,
                    (unsigned int)*reinterpret_cast<unsigned short*>(&hb));
          out[(size_t)row*(HDIM*T_STEPS) + (size_t)j*T_STEPS + t1] = hn;
        }
      }
    }

    gbar(flags, ++bc);   // B2: h published
  }
}

// ---------------------------------------------------------------------------
extern "C" void kernel_launch(void* const* d_in, const int* in_sizes, int n_in,
                              void* d_out, int out_size, void* d_ws, size_t ws_size,
                              hipStream_t stream) {
  const float* xs  = (const float*)d_in[0];
  const float* Wx0 = (const float*)d_in[1];
  const float* Wh0 = (const float*)d_in[2];
  const float* gx0g = (const float*)d_in[3];
  const float* gx0b = (const float*)d_in[4];
  const float* gh0g = (const float*)d_in[5];
  const float* gh0b = (const float*)d_in[6];
  const float* Wx1 = (const float*)d_in[7];
  const float* Wh1 = (const float*)d_in[8];
  const float* gx1g = (const float*)d_in[9];
  const float* gx1b = (const float*)d_in[10];
  const float* gh1g = (const float*)d_in[11];
  const float* gh1b = (const float*)d_in[12];

  unsigned char* ws = (unsigned char*)d_ws;
  float* out = (float*)d_out;
  (void)in_sizes; (void)n_in; (void)out_size; (void)ws_size;

  // zero flags + stat partials + h0/h1 + statsX (head region)
  k_zero<<<256, 256, 0, stream>>>((unsigned int*)ws, (int)(OFF_WH0HI/4));

  // weight hi/lo conversion
  k_conv<<<512, 256, 0, stream>>>(Wh0, (__hip_bfloat16*)(ws+OFF_WH0HI), (__hip_bfloat16*)(ws+OFF_WH0LO), THREE_H*HDIM);
  k_conv<<<512, 256, 0, stream>>>(Wx1, (__hip_bfloat16*)(ws+OFF_WX1HI), (__hip_bfloat16*)(ws+OFF_WX1LO), THREE_H*HDIM);
  k_conv<<<512, 256, 0, stream>>>(Wh1, (__hip_bfloat16*)(ws+OFF_WH1HI), (__hip_bfloat16*)(ws+OFF_WH1LO), THREE_H*HDIM);
  k_conv<<<512, 256, 0, stream>>>(Wx0, (__hip_bfloat16*)(ws+OFF_WX0HI), (__hip_bfloat16*)(ws+OFF_WX0LO), THREE_H*CINDIM);

  // xs transpose -> xsT bf16
  k_tr<<<4096, 256, 0, stream>>>(xs, (__hip_bfloat16*)(ws+OFF_XST));

  // x-path GEMM for all timesteps
  k_xgemm<<<16384, 256, 0, stream>>>(ws);
  k_statsx<<<256, 256, 0, stream>>>((float*)(ws+OFF_STATSX));

  // persistent recurrence
  k_rnn<<<NBLK, 256, 0, stream>>>(gx0g, gx0b, gh0g, gh0b, gx1g, gx1b, gh1g, gh1b, ws, out);
}

// Round 6
// 13017.574 us; speedup vs baseline: 2.8959x; 1.4327x over previous
//
#include <hip/hip_runtime.h>
#include <hip/hip_bf16.h>
#include <cstdint>
#include <cstddef>

// ---------------------------------------------------------------------------
// StackedLayerNormGRU  (B=64, C_IN=256, H=512, T=1024)
//
// Round 6: R5's register-resident-weight design, register-safe.
//  - 64 blocks: 32 "A" (layer-0, Wh0 strip in regs, ~250 VGPR) +
//               32 "B" (layer-1, Wx1+Wh1 strips in regs, sequential GEMMs
//               reusing one AR set, ~380 VGPR — no spill).
//  - Proven R4 protocol: 2 distributed-flag barriers/step, sc0 sc1 for all
//    cross-block data, stat partials + tree reduce (no atomics).
// ---------------------------------------------------------------------------

#define NBATCH 64
#define HDIM   512
#define THREE_H 1536
#define CINDIM 256
#define T_STEPS 1024
#define EPSLN 1e-5f
#define NBLK 64   // 32 A-blocks (L0) + 32 B-blocks (L1)

typedef __bf16 bf8v __attribute__((ext_vector_type(8)));
typedef float f4 __attribute__((ext_vector_type(4)));
typedef float f2 __attribute__((ext_vector_type(2)));
typedef unsigned int u32x4 __attribute__((ext_vector_type(4)));

// ---- workspace layout (bytes) ----
static constexpr size_t OFF_BAR    = 0;          // 64 flags x 128B = 8192
static constexpr size_t OFF_ST0P   = 8192;       // [64][32][2] f32 = 16384
static constexpr size_t OFF_ST1P   = 24576;      // [64][32][2] f32
static constexpr size_t OFF_ST2P   = 40960;      // [64][32][2] f32
static constexpr size_t OFF_H0BF   = 57344;      // 64*512 bf16 = 65536
static constexpr size_t OFF_H1BF   = 122880;     // 65536
static constexpr size_t OFF_STATSX = 188416;     // [1024][64][2] f32 = 524288
static constexpr size_t OFF_WH0HI  = 712704;     // 1536*512 bf16 = 1572864 each
static constexpr size_t OFF_WH0LO  = OFF_WH0HI + 1572864;
static constexpr size_t OFF_WX1HI  = OFF_WH0LO + 1572864;
static constexpr size_t OFF_WX1LO  = OFF_WX1HI + 1572864;
static constexpr size_t OFF_WH1HI  = OFF_WX1LO + 1572864;
static constexpr size_t OFF_WH1LO  = OFF_WH1HI + 1572864;
static constexpr size_t OFF_WX0HI  = OFF_WH1LO + 1572864;   // 1536*256 bf16
static constexpr size_t OFF_WX0LO  = OFF_WX0HI + 786432;
static constexpr size_t OFF_XST    = OFF_WX0LO + 786432;    // 33554432
static constexpr size_t OFF_GX0    = OFF_XST + 33554432;    // 201326592

__device__ __forceinline__ f4 mf(bf8v a, bf8v b, f4 c){
  return __builtin_amdgcn_mfma_f32_16x16x32_bf16(a, b, c, 0, 0, 0);
}
__device__ __forceinline__ float sigf(float x){ return 1.0f/(1.0f + __expf(-x)); }
__device__ __forceinline__ float tanhfast(float x){ return 1.0f - 2.0f/(__expf(2.0f*x) + 1.0f); }

// ---- device-coherent (MALL) access helpers ----
__device__ __forceinline__ bf8v ld16_cross(const void* p){
  u32x4 t;
  asm volatile("global_load_dwordx4 %0, %1, off sc0 sc1" : "=v"(t) : "v"(p));
  return __builtin_bit_cast(bf8v, t);
}
__device__ __forceinline__ f4 ld16f_cross(const float* p){
  f4 v;
  asm volatile("global_load_dwordx4 %0, %1, off sc0 sc1" : "=v"(v) : "v"(p));
  return v;
}
__device__ __forceinline__ void st2_cross(__hip_bfloat16* p, unsigned int u){
  asm volatile("global_store_short %0, %1, off sc0 sc1" :: "v"(p), "v"(u));
}
__device__ __forceinline__ void st8f_cross(float* p, f2 v){
  asm volatile("global_store_dwordx2 %0, %1, off sc0 sc1" :: "v"(p), "v"(v));
}
__device__ __forceinline__ void vm_drain(){
  asm volatile("s_waitcnt vmcnt(0)" ::: "memory");
  __builtin_amdgcn_sched_barrier(0);
}

// ---- distributed flag barrier: 64 flags, 128B apart, epoch-numbered ----
__device__ __forceinline__ void gbar(unsigned int* flags, unsigned int target){
  asm volatile("s_waitcnt vmcnt(0) lgkmcnt(0)" ::: "memory");
  __syncthreads();
  if (threadIdx.x == 0){
    unsigned int* myf = flags + (size_t)blockIdx.x * 32;
    asm volatile("global_store_dword %0, %1, off sc0 sc1" :: "v"(myf), "v"(target) : "memory");
  }
  const int lane = threadIdx.x & 63;
  const unsigned int* pf = flags + (size_t)lane * 32;
  for (;;){
    unsigned int v;
    asm volatile("global_load_dword %0, %1, off sc0 sc1\n\ts_waitcnt vmcnt(0)"
                 : "=v"(v) : "v"(pf) : "memory");
    if (__all((int)(v >= target))) break;
    __builtin_amdgcn_s_sleep(1);
  }
}

// ---- K0: zero head of workspace ----
__global__ void k_zero(unsigned int* p, int nwords){
  for (int i = blockIdx.x*blockDim.x + threadIdx.x; i < nwords; i += gridDim.x*blockDim.x)
    p[i] = 0u;
}

// ---- K1: fp32 weight -> bf16 hi/lo split ----
__global__ void k_conv(const float* __restrict__ src, __hip_bfloat16* __restrict__ hi,
                       __hip_bfloat16* __restrict__ lo, int n){
  for (int i = blockIdx.x*blockDim.x + threadIdx.x; i < n; i += gridDim.x*blockDim.x){
    float w = src[i];
    __hip_bfloat16 h = __float2bfloat16(w);
    hi[i] = h;
    lo[i] = __float2bfloat16(w - __bfloat162float(h));
  }
}

// ---- K1b: xs [B][C][T] f32 -> xsT [T][B][C] bf16 ----
__global__ void k_tr(const float* __restrict__ xs, __hip_bfloat16* __restrict__ xsT){
  const int total = NBATCH * CINDIM * (T_STEPS/4);
  for (int idx = blockIdx.x*blockDim.x + threadIdx.x; idx < total; idx += gridDim.x*blockDim.x){
    int b  = idx >> 16;
    int c  = (idx >> 8) & 255;
    int t4 = idx & 255;
    const float4 v = *(const float4*)(xs + ((size_t)b*CINDIM + c)*T_STEPS + t4*4);
    float vv[4] = {v.x, v.y, v.z, v.w};
    #pragma unroll
    for (int i = 0; i < 4; ++i)
      xsT[(size_t)(4*t4 + i)*(NBATCH*CINDIM) + b*CINDIM + c] = __float2bfloat16(vv[i]);
  }
}

// ---- K2: gate_x0 raw GEMM + stat atomics (proven R4 code) ----
__global__ __launch_bounds__(256,1) void k_xgemm(unsigned char* __restrict__ ws){
  const int tid = threadIdx.x;
  const int bx = blockIdx.x;
  const int t = bx >> 4, s = bx & 15;
  const int lane = tid & 63, w = tid >> 6, l15 = lane & 15, lg = lane >> 4;

  const __hip_bfloat16* X  = (const __hip_bfloat16*)(ws + OFF_XST) + (size_t)t*(NBATCH*CINDIM);
  const __hip_bfloat16* WH = (const __hip_bfloat16*)(ws + OFF_WX0HI);
  const __hip_bfloat16* WL = (const __hip_bfloat16*)(ws + OFF_WX0LO);
  float* statsX = (float*)(ws + OFF_STATSX);
  __hip_bfloat16* GX0 = (__hip_bfloat16*)(ws + OFF_GX0) + (size_t)t*(NBATCH*THREE_H);

  __shared__ __hip_bfloat16 SB[2][2][96][72];

  f4 acc[6];
  #pragma unroll
  for (int i = 0; i < 6; ++i) acc[i] = f4{0.f,0.f,0.f,0.f};

  bf8v A0[8];
  #pragma unroll
  for (int kk = 0; kk < 8; ++kk)
    A0[kk] = *(const bf8v*)(X + (16*w + l15)*CINDIM + kk*32 + 8*lg);

  bf8v pre[6];
  #pragma unroll
  for (int rep = 0; rep < 6; ++rep){
    int idx = tid + rep*256; int half = idx >= 768 ? 1 : 0; int i2 = idx - half*768;
    int rr = i2 >> 3, ko = (i2 & 7)*8;
    int j = 32*s + (rr & 31) + 512*(rr >> 5);
    const __hip_bfloat16* sp = (half ? WL : WH) + (size_t)j*CINDIM;
    pre[rep] = *(const bf8v*)(sp + ko);
  }
  #pragma unroll
  for (int chk = 0; chk < 4; ++chk){
    #pragma unroll
    for (int rep = 0; rep < 6; ++rep){
      int idx = tid + rep*256; int half = idx >= 768 ? 1 : 0; int i2 = idx - half*768;
      int rr = i2 >> 3, ko = (i2 & 7)*8;
      *(bf8v*)&SB[chk & 1][half][rr][ko] = pre[rep];
    }
    __syncthreads();
    if (chk < 3){
      #pragma unroll
      for (int rep = 0; rep < 6; ++rep){
        int idx = tid + rep*256; int half = idx >= 768 ? 1 : 0; int i2 = idx - half*768;
        int rr = i2 >> 3, ko = (i2 & 7)*8;
        int j = 32*s + (rr & 31) + 512*(rr >> 5);
        const __hip_bfloat16* sp = (half ? WL : WH) + (size_t)j*CINDIM;
        pre[rep] = *(const bf8v*)(sp + (chk+1)*64 + ko);
      }
    }
    #pragma unroll
    for (int sub = 0; sub < 2; ++sub){
      int kk = 2*chk + sub; int ko = 32*sub + 8*lg;
      bf8v a = A0[kk];
      #pragma unroll
      for (int nf = 0; nf < 6; ++nf){
        bf8v bh = *(const bf8v*)&SB[chk & 1][0][16*nf + l15][ko];
        bf8v bl = *(const bf8v*)&SB[chk & 1][1][16*nf + l15][ko];
        acc[nf] = mf(a, bh, acc[nf]);
        acc[nf] = mf(a, bl, acc[nf]);
      }
    }
  }

  #pragma unroll
  for (int r = 0; r < 4; ++r){
    int row = 16*w + 4*lg + r;
    float sm = 0.f, sq = 0.f;
    #pragma unroll
    for (int nf = 0; nf < 6; ++nf){
      float v = acc[nf][r];
      sm += v; sq += v*v;
      int tc = 16*nf + l15;
      int j = 32*s + (tc & 31) + 512*(tc >> 5);
      GX0[(size_t)row*THREE_H + j] = __float2bfloat16(v);
    }
    #pragma unroll
    for (int m = 1; m < 16; m <<= 1){ sm += __shfl_xor(sm, m); sq += __shfl_xor(sq, m); }
    if (l15 == 0){
      atomicAdd(&statsX[((size_t)t*64 + row)*2 + 0], sm);
      atomicAdd(&statsX[((size_t)t*64 + row)*2 + 1], sq);
    }
  }
}

// ---- K2b: finalize x stats ----
__global__ void k_statsx(float* __restrict__ sx){
  int i = blockIdx.x*blockDim.x + threadIdx.x;
  if (i < T_STEPS*NBATCH){
    float s = sx[2*i], q = sx[2*i+1];
    float m = s * (1.0f/1536.0f);
    float v = fmaxf(q * (1.0f/1536.0f) - m*m, 0.0f);
    sx[2*i] = m;
    sx[2*i+1] = rsqrtf(v + EPSLN);
  }
}

// ===========================================================================
// K3 worker paths.  red: [w'][g][rt][lane] f4 (48 KiB).  BC: f2[64] each.
// ===========================================================================

// ---- A-path: layer-0 recurrence, Wh0 strip in registers (~250 VGPR) ----
__device__ __forceinline__ void runA(
    int s, unsigned char* ws, f4* red, f2* BC0,
    const float* gxg, const float* gxb, const float* ghg, const float* ghb)
{
  const int tid = threadIdx.x, lane = tid & 63, w = tid >> 6;
  const int l15 = lane & 15, lg = (lane >> 4) & 3;

  unsigned int* flags = (unsigned int*)(ws + OFF_BAR);
  float* st0P = (float*)(ws + OFF_ST0P);
  __hip_bfloat16* h0bf = (__hip_bfloat16*)(ws + OFF_H0BF);
  const float* statsX = (const float*)(ws + OFF_STATSX);
  const __hip_bfloat16* GX0 = (const __hip_bfloat16*)(ws + OFF_GX0);

  // register-resident Wh0 strip (this block's 16-col gate triple, wave K-quarter)
  bf8v BW[3][4][2];
  {
    const __hip_bfloat16* hi = (const __hip_bfloat16*)(ws + OFF_WH0HI);
    const __hip_bfloat16* lo = (const __hip_bfloat16*)(ws + OFF_WH0LO);
    #pragma unroll
    for (int g = 0; g < 3; ++g){
      const size_t j = (size_t)(16*s + l15 + 512*g);
      #pragma unroll
      for (int kt = 0; kt < 4; ++kt){
        const size_t ko = (size_t)((4*w + kt)*32 + 8*lg);
        BW[g][kt][0] = *(const bf8v*)(hi + j*HDIM + ko);
        BW[g][kt][1] = *(const bf8v*)(lo + j*HDIM + ko);
      }
    }
  }
  float PXg[3], PXb[3], PHg[3], PHb[3];
  #pragma unroll
  for (int g = 0; g < 3; ++g){
    int j = 16*s + l15 + 512*g;
    PXg[g] = gxg[j]; PXb[g] = gxb[j]; PHg[g] = ghg[j]; PHb[g] = ghb[j];
  }

  float hp[4] = {0.f,0.f,0.f,0.f};
  unsigned int bc = 0;

  for (int tau = 0; tau <= T_STEPS; ++tau){
    const bool act = (tau < T_STEPS);
    f4 zx[3];
    float gxraw[3][4], mxv[4], rsxv[4];

    if (act){
      bf8v AR[4][4];
      #pragma unroll
      for (int rt = 0; rt < 4; ++rt)
        #pragma unroll
        for (int kt = 0; kt < 4; ++kt)
          AR[rt][kt] = ld16_cross(h0bf + (size_t)(16*rt + l15)*HDIM + (4*w + kt)*32 + 8*lg);
      vm_drain();

      f4 AC[3][4];
      #pragma unroll
      for (int g = 0; g < 3; ++g)
        #pragma unroll
        for (int rt = 0; rt < 4; ++rt) AC[g][rt] = f4{0.f,0.f,0.f,0.f};
      #pragma unroll
      for (int kt = 0; kt < 4; ++kt)
        #pragma unroll
        for (int g = 0; g < 3; ++g)
          #pragma unroll
          for (int rt = 0; rt < 4; ++rt){
            AC[g][rt] = mf(AR[rt][kt], BW[g][kt][0], AC[g][rt]);
            AC[g][rt] = mf(AR[rt][kt], BW[g][kt][1], AC[g][rt]);
          }

      // prefetch gate_x0 raw + stats (plain cached loads, consumed in P2)
      #pragma unroll
      for (int r = 0; r < 4; ++r){
        int row = 16*w + 4*lg + r;
        mxv[r]  = statsX[((size_t)tau*64 + row)*2 + 0];
        rsxv[r] = statsX[((size_t)tau*64 + row)*2 + 1];
        #pragma unroll
        for (int g = 0; g < 3; ++g)
          gxraw[g][r] = __bfloat162float(
            GX0[(size_t)tau*(NBATCH*THREE_H) + (size_t)row*THREE_H + (16*s + l15 + 512*g)]);
      }

      // K-reduce
      #pragma unroll
      for (int g = 0; g < 3; ++g)
        #pragma unroll
        for (int rt = 0; rt < 4; ++rt)
          red[((w*3 + g)*4 + rt)*64 + lane] = AC[g][rt];
      __syncthreads();
      #pragma unroll
      for (int g = 0; g < 3; ++g){
        f4 a = red[((0*3 + g)*4 + w)*64 + lane];
        a += red[((1*3 + g)*4 + w)*64 + lane];
        a += red[((2*3 + g)*4 + w)*64 + lane];
        a += red[((3*3 + g)*4 + w)*64 + lane];
        zx[g] = a;
      }

      // stat partials
      #pragma unroll
      for (int r = 0; r < 4; ++r){
        float s1 = zx[0][r] + zx[1][r] + zx[2][r];
        float q1 = zx[0][r]*zx[0][r] + zx[1][r]*zx[1][r] + zx[2][r]*zx[2][r];
        #pragma unroll
        for (int m = 1; m < 16; m <<= 1){ s1 += __shfl_xor(s1, m); q1 += __shfl_xor(q1, m); }
        if (l15 == 0){
          int row = 16*w + 4*lg + r;
          st8f_cross(st0P + ((size_t)row*32 + s)*2, f2{s1, q1});
        }
      }
    }

    gbar(flags, ++bc);   // B1

    if (act){
      {
        int row = tid >> 2, q = tid & 3;
        const float* bp = st0P + (size_t)row*64 + q*16;
        f4 v0 = ld16f_cross(bp),   v1 = ld16f_cross(bp+4);
        f4 v2 = ld16f_cross(bp+8), v3 = ld16f_cross(bp+12);
        vm_drain();
        float sm = v0[0]+v0[2]+v1[0]+v1[2]+v2[0]+v2[2]+v3[0]+v3[2];
        float sq = v0[1]+v0[3]+v1[1]+v1[3]+v2[1]+v2[3]+v3[1]+v3[3];
        sm += __shfl_xor(sm,1); sq += __shfl_xor(sq,1);
        sm += __shfl_xor(sm,2); sq += __shfl_xor(sq,2);
        if (q == 0){
          float m = sm*(1.0f/1536.0f);
          float vv = fmaxf(sq*(1.0f/1536.0f) - m*m, 0.0f);
          BC0[row] = f2{m, rsqrtf(vv + EPSLN)};
        }
      }
      __syncthreads();
      #pragma unroll
      for (int r = 0; r < 4; ++r){
        int row = 16*w + 4*lg + r;
        f2 mr = BC0[row];
        float m = mr[0], rs = mr[1];
        float ghr = (zx[0][r]-m)*rs*PHg[0] + PHb[0];
        float ghi = (zx[1][r]-m)*rs*PHg[1] + PHb[1];
        float ghn = (zx[2][r]-m)*rs*PHg[2] + PHb[2];
        float gxr = (gxraw[0][r] - mxv[r])*rsxv[r]*PXg[0] + PXb[0];
        float gxi = (gxraw[1][r] - mxv[r])*rsxv[r]*PXg[1] + PXb[1];
        float gxn = (gxraw[2][r] - mxv[r])*rsxv[r]*PXg[2] + PXb[2];
        float rg = sigf(gxr + ghr);
        float ig = sigf(gxi + ghi);
        float nn = tanhfast(gxn + rg*ghn);
        float hn = nn + ig*(hp[r] - nn);
        hp[r] = hn;
        __hip_bfloat16 hb = __float2bfloat16(hn);
        st2_cross(h0bf + (size_t)row*HDIM + 16*s + l15,
                  (unsigned int)*reinterpret_cast<unsigned short*>(&hb));
      }
    }

    gbar(flags, ++bc);   // B2
  }
}

// ---- B-path: layer-1, Wx1+Wh1 strips in regs, sequential GEMMs (~380 VGPR) ----
__device__ __forceinline__ void runB(
    int s, unsigned char* ws, f4* red, f2* BC1, f2* BC2,
    const float* gxg, const float* gxb, const float* ghg, const float* ghb,
    float* out)
{
  const int tid = threadIdx.x, lane = tid & 63, w = tid >> 6;
  const int l15 = lane & 15, lg = (lane >> 4) & 3;

  unsigned int* flags = (unsigned int*)(ws + OFF_BAR);
  float* st1P = (float*)(ws + OFF_ST1P);
  float* st2P = (float*)(ws + OFF_ST2P);
  __hip_bfloat16* h0bf = (__hip_bfloat16*)(ws + OFF_H0BF);
  __hip_bfloat16* h1bf = (__hip_bfloat16*)(ws + OFF_H1BF);

  // register-resident Wx1 (slots 0-2) + Wh1 (slots 3-5) strips
  bf8v BW[6][4][2];
  {
    const __hip_bfloat16* hix = (const __hip_bfloat16*)(ws + OFF_WX1HI);
    const __hip_bfloat16* lox = (const __hip_bfloat16*)(ws + OFF_WX1LO);
    const __hip_bfloat16* hih = (const __hip_bfloat16*)(ws + OFF_WH1HI);
    const __hip_bfloat16* loh = (const __hip_bfloat16*)(ws + OFF_WH1LO);
    #pragma unroll
    for (int g = 0; g < 3; ++g){
      const size_t j = (size_t)(16*s + l15 + 512*g);
      #pragma unroll
      for (int kt = 0; kt < 4; ++kt){
        const size_t ko = (size_t)((4*w + kt)*32 + 8*lg);
        BW[g][kt][0]   = *(const bf8v*)(hix + j*HDIM + ko);
        BW[g][kt][1]   = *(const bf8v*)(lox + j*HDIM + ko);
        BW[3+g][kt][0] = *(const bf8v*)(hih + j*HDIM + ko);
        BW[3+g][kt][1] = *(const bf8v*)(loh + j*HDIM + ko);
      }
    }
  }
  float PXg[3], PXb[3], PHg[3], PHb[3];
  #pragma unroll
  for (int g = 0; g < 3; ++g){
    int j = 16*s + l15 + 512*g;
    PXg[g] = gxg[j]; PXb[g] = gxb[j]; PHg[g] = ghg[j]; PHb[g] = ghb[j];
  }

  float hp[4] = {0.f,0.f,0.f,0.f};
  unsigned int bc = 0;

  for (int tau = 0; tau <= T_STEPS; ++tau){
    const bool act = (tau >= 1);
    f4 zx[3], zh[3];

    if (act){
      // ---- GEMM 1: z_x1[tau-1] = h0[tau-1] @ Wx1^T ----
      bf8v AR[4][4];
      #pragma unroll
      for (int rt = 0; rt < 4; ++rt)
        #pragma unroll
        for (int kt = 0; kt < 4; ++kt)
          AR[rt][kt] = ld16_cross(h0bf + (size_t)(16*rt + l15)*HDIM + (4*w + kt)*32 + 8*lg);
      vm_drain();

      f4 AC[3][4];
      #pragma unroll
      for (int g = 0; g < 3; ++g)
        #pragma unroll
        for (int rt = 0; rt < 4; ++rt) AC[g][rt] = f4{0.f,0.f,0.f,0.f};
      #pragma unroll
      for (int kt = 0; kt < 4; ++kt)
        #pragma unroll
        for (int g = 0; g < 3; ++g)
          #pragma unroll
          for (int rt = 0; rt < 4; ++rt){
            AC[g][rt] = mf(AR[rt][kt], BW[g][kt][0], AC[g][rt]);
            AC[g][rt] = mf(AR[rt][kt], BW[g][kt][1], AC[g][rt]);
          }
      #pragma unroll
      for (int g = 0; g < 3; ++g)
        #pragma unroll
        for (int rt = 0; rt < 4; ++rt)
          red[((w*3 + g)*4 + rt)*64 + lane] = AC[g][rt];

      // issue h1 loads now (overlap with LDS reduce), reusing AR
      #pragma unroll
      for (int rt = 0; rt < 4; ++rt)
        #pragma unroll
        for (int kt = 0; kt < 4; ++kt)
          AR[rt][kt] = ld16_cross(h1bf + (size_t)(16*rt + l15)*HDIM + (4*w + kt)*32 + 8*lg);

      __syncthreads();
      #pragma unroll
      for (int g = 0; g < 3; ++g){
        f4 a = red[((0*3 + g)*4 + w)*64 + lane];
        a += red[((1*3 + g)*4 + w)*64 + lane];
        a += red[((2*3 + g)*4 + w)*64 + lane];
        a += red[((3*3 + g)*4 + w)*64 + lane];
        zx[g] = a;
      }
      __syncthreads();   // all reads of red done before overwrite

      // ---- GEMM 2: z_h1[tau-1] = h1[tau-2] @ Wh1^T ----
      vm_drain();
      #pragma unroll
      for (int g = 0; g < 3; ++g)
        #pragma unroll
        for (int rt = 0; rt < 4; ++rt) AC[g][rt] = f4{0.f,0.f,0.f,0.f};
      #pragma unroll
      for (int kt = 0; kt < 4; ++kt)
        #pragma unroll
        for (int g = 0; g < 3; ++g)
          #pragma unroll
          for (int rt = 0; rt < 4; ++rt){
            AC[g][rt] = mf(AR[rt][kt], BW[3+g][kt][0], AC[g][rt]);
            AC[g][rt] = mf(AR[rt][kt], BW[3+g][kt][1], AC[g][rt]);
          }
      #pragma unroll
      for (int g = 0; g < 3; ++g)
        #pragma unroll
        for (int rt = 0; rt < 4; ++rt)
          red[((w*3 + g)*4 + rt)*64 + lane] = AC[g][rt];
      __syncthreads();
      #pragma unroll
      for (int g = 0; g < 3; ++g){
        f4 a = red[((0*3 + g)*4 + w)*64 + lane];
        a += red[((1*3 + g)*4 + w)*64 + lane];
        a += red[((2*3 + g)*4 + w)*64 + lane];
        a += red[((3*3 + g)*4 + w)*64 + lane];
        zh[g] = a;
      }

      // stat partials for both GEMMs
      #pragma unroll
      for (int r = 0; r < 4; ++r){
        float s1 = zx[0][r] + zx[1][r] + zx[2][r];
        float q1 = zx[0][r]*zx[0][r] + zx[1][r]*zx[1][r] + zx[2][r]*zx[2][r];
        float s2 = zh[0][r] + zh[1][r] + zh[2][r];
        float q2 = zh[0][r]*zh[0][r] + zh[1][r]*zh[1][r] + zh[2][r]*zh[2][r];
        #pragma unroll
        for (int m = 1; m < 16; m <<= 1){
          s1 += __shfl_xor(s1, m); q1 += __shfl_xor(q1, m);
          s2 += __shfl_xor(s2, m); q2 += __shfl_xor(q2, m);
        }
        if (l15 == 0){
          int row = 16*w + 4*lg + r;
          st8f_cross(st1P + ((size_t)row*32 + s)*2, f2{s1, q1});
          st8f_cross(st2P + ((size_t)row*32 + s)*2, f2{s2, q2});
        }
      }
    }

    gbar(flags, ++bc);   // B1

    if (act){
      const int t1 = tau - 1;
      {
        int row = tid >> 2, q = tid & 3;
        const float* b1 = st1P + (size_t)row*64 + q*16;
        const float* b2 = st2P + (size_t)row*64 + q*16;
        f4 a0 = ld16f_cross(b1),   a1 = ld16f_cross(b1+4);
        f4 a2 = ld16f_cross(b1+8), a3 = ld16f_cross(b1+12);
        f4 c0 = ld16f_cross(b2),   c1 = ld16f_cross(b2+4);
        f4 c2 = ld16f_cross(b2+8), c3 = ld16f_cross(b2+12);
        vm_drain();
        float s1 = a0[0]+a0[2]+a1[0]+a1[2]+a2[0]+a2[2]+a3[0]+a3[2];
        float q1 = a0[1]+a0[3]+a1[1]+a1[3]+a2[1]+a2[3]+a3[1]+a3[3];
        float s2 = c0[0]+c0[2]+c1[0]+c1[2]+c2[0]+c2[2]+c3[0]+c3[2];
        float q2 = c0[1]+c0[3]+c1[1]+c1[3]+c2[1]+c2[3]+c3[1]+c3[3];
        s1 += __shfl_xor(s1,1); q1 += __shfl_xor(q1,1);
        s1 += __shfl_xor(s1,2); q1 += __shfl_xor(q1,2);
        s2 += __shfl_xor(s2,1); q2 += __shfl_xor(q2,1);
        s2 += __shfl_xor(s2,2); q2 += __shfl_xor(q2,2);
        if (q == 0){
          float m1 = s1*(1.0f/1536.0f);
          float v1 = fmaxf(q1*(1.0f/1536.0f) - m1*m1, 0.0f);
          BC1[row] = f2{m1, rsqrtf(v1 + EPSLN)};
          float m2 = s2*(1.0f/1536.0f);
          float v2 = fmaxf(q2*(1.0f/1536.0f) - m2*m2, 0.0f);
          BC2[row] = f2{m2, rsqrtf(v2 + EPSLN)};
        }
      }
      __syncthreads();
      #pragma unroll
      for (int r = 0; r < 4; ++r){
        int row = 16*w + 4*lg + r;
        f2 m1 = BC1[row], m2 = BC2[row];
        float gxr = (zx[0][r] - m1[0])*m1[1]*PXg[0] + PXb[0];
        float gxi = (zx[1][r] - m1[0])*m1[1]*PXg[1] + PXb[1];
        float gxn = (zx[2][r] - m1[0])*m1[1]*PXg[2] + PXb[2];
        float ghr = (zh[0][r] - m2[0])*m2[1]*PHg[0] + PHb[0];
        float ghi = (zh[1][r] - m2[0])*m2[1]*PHg[1] + PHb[1];
        float ghn = (zh[2][r] - m2[0])*m2[1]*PHg[2] + PHb[2];
        float rg = sigf(gxr + ghr);
        float ig = sigf(gxi + ghi);
        float nn = tanhfast(gxn + rg*ghn);
        float hn = nn + ig*(hp[r] - nn);
        hp[r] = hn;
        int j = 16*s + l15;
        __hip_bfloat16 hb = __float2bfloat16(hn);
        st2_cross(h1bf + (size_t)row*HDIM + j,
                  (unsigned int)*reinterpret_cast<unsigned short*>(&hb));
        out[(size_t)row*(HDIM*T_STEPS) + (size_t)j*T_STEPS + t1] = hn;
      }
    }

    gbar(flags, ++bc);   // B2
  }
}

// ---- K3: persistent recurrent kernel, 64 blocks x 256 threads ----
__global__ __launch_bounds__(256,1) void k_rnn(
    const float* __restrict__ gx0g, const float* __restrict__ gx0b,
    const float* __restrict__ gh0g, const float* __restrict__ gh0b,
    const float* __restrict__ gx1g, const float* __restrict__ gx1b,
    const float* __restrict__ gh1g, const float* __restrict__ gh1b,
    unsigned char* __restrict__ ws, float* __restrict__ out)
{
  __shared__ f4 red[4*3*4*64];   // 48 KiB
  __shared__ f2 BCa[64];
  __shared__ f2 BCb[64];

  const int bi = blockIdx.x;
  if (bi < 32)
    runA(bi, ws, red, BCa, gx0g, gx0b, gh0g, gh0b);
  else
    runB(bi - 32, ws, red, BCa, BCb, gx1g, gx1b, gh1g, gh1b, out);
}

// ---------------------------------------------------------------------------
extern "C" void kernel_launch(void* const* d_in, const int* in_sizes, int n_in,
                              void* d_out, int out_size, void* d_ws, size_t ws_size,
                              hipStream_t stream) {
  const float* xs  = (const float*)d_in[0];
  const float* Wx0 = (const float*)d_in[1];
  const float* Wh0 = (const float*)d_in[2];
  const float* gx0g = (const float*)d_in[3];
  const float* gx0b = (const float*)d_in[4];
  const float* gh0g = (const float*)d_in[5];
  const float* gh0b = (const float*)d_in[6];
  const float* Wx1 = (const float*)d_in[7];
  const float* Wh1 = (const float*)d_in[8];
  const float* gx1g = (const float*)d_in[9];
  const float* gx1b = (const float*)d_in[10];
  const float* gh1g = (const float*)d_in[11];
  const float* gh1b = (const float*)d_in[12];

  unsigned char* ws = (unsigned char*)d_ws;
  float* out = (float*)d_out;
  (void)in_sizes; (void)n_in; (void)out_size; (void)ws_size;

  // zero flags + stat partials + h0/h1 + statsX (head region)
  k_zero<<<256, 256, 0, stream>>>((unsigned int*)ws, (int)(OFF_WH0HI/4));

  // weight hi/lo conversion
  k_conv<<<512, 256, 0, stream>>>(Wh0, (__hip_bfloat16*)(ws+OFF_WH0HI), (__hip_bfloat16*)(ws+OFF_WH0LO), THREE_H*HDIM);
  k_conv<<<512, 256, 0, stream>>>(Wx1, (__hip_bfloat16*)(ws+OFF_WX1HI), (__hip_bfloat16*)(ws+OFF_WX1LO), THREE_H*HDIM);
  k_conv<<<512, 256, 0, stream>>>(Wh1, (__hip_bfloat16*)(ws+OFF_WH1HI), (__hip_bfloat16*)(ws+OFF_WH1LO), THREE_H*HDIM);
  k_conv<<<512, 256, 0, stream>>>(Wx0, (__hip_bfloat16*)(ws+OFF_WX0HI), (__hip_bfloat16*)(ws+OFF_WX0LO), THREE_H*CINDIM);

  // xs transpose -> xsT bf16
  k_tr<<<4096, 256, 0, stream>>>(xs, (__hip_bfloat16*)(ws+OFF_XST));

  // x-path GEMM for all timesteps
  k_xgemm<<<16384, 256, 0, stream>>>(ws);
  k_statsx<<<256, 256, 0, stream>>>((float*)(ws+OFF_STATSX));

  // persistent recurrence
  k_rnn<<<NBLK, 256, 0, stream>>>(gx0g, gx0b, gh0g, gh0b, gx1g, gx1b, gh1g, gh1b, ws, out);
}